// Round 4
// baseline (1540.712 us; speedup 1.0000x reference)
//
#include <hip/hip_runtime.h>
#include <hip/hip_bf16.h>
#include <stdint.h>
#include <stddef.h>

// ---------------- problem dims ----------------
#define NB 16
#define NS 256
#define NH 512
#define NE 256
#define NV 32000
#define NM (NB*NS)        // 4096 flattened rows, m = b*256 + s
#define N3H 1536
#define GRU_WGS 64
#define DEC_WGS 192
#define NCT 250           // 32000 / 128 decoder col-tiles

typedef __attribute__((ext_vector_type(8))) short short8v;
typedef __attribute__((ext_vector_type(4))) float float4v;
typedef __attribute__((address_space(1))) const unsigned int gas_u32;
typedef __attribute__((address_space(3))) unsigned int las_u32;

static __device__ __forceinline__ unsigned short f2bf(float f) {
  __hip_bfloat16 h = __float2bfloat16(f);
  return *reinterpret_cast<unsigned short*>(&h);
}
static __device__ __forceinline__ float bf2f(unsigned short u) {
  union { unsigned int u; float f; } c;
  c.u = ((unsigned int)u) << 16;
  return c.f;
}
static __device__ __forceinline__ float fast_tanh(float x) {
  float t = __expf(2.f * x);
  return (t - 1.f) / (t + 1.f);
}

// ---------------- embedding gather + convert to bf16 ----------------
__global__ void gather_emb(const int* __restrict__ x, const float* __restrict__ E,
                           unsigned short* __restrict__ A) {
  int m = blockIdx.x * 4 + (threadIdx.x >> 6);
  int lane = threadIdx.x & 63;
  int t = x[m];
  float4 v = reinterpret_cast<const float4*>(E + (size_t)t * NE)[lane];
  ushort4 o = make_ushort4(f2bf(v.x), f2bf(v.y), f2bf(v.z), f2bf(v.w));
  reinterpret_cast<ushort4*>(A + (size_t)m * NE)[lane] = o;
}

// ---------------- tiled transpose, f32 in -> (bf16|f32) out ----------------
template<typename T>
__global__ void transpose_conv(const float* __restrict__ in, T* __restrict__ out,
                               int R, int C) {
  __shared__ float tile[32][33];
  int c0 = blockIdx.x * 32, r0 = blockIdx.y * 32;
  int tx = threadIdx.x, ty = threadIdx.y;
  #pragma unroll
  for (int i = 0; i < 32; i += 8)
    tile[ty + i][tx] = in[(size_t)(r0 + ty + i) * C + (c0 + tx)];
  __syncthreads();
  #pragma unroll
  for (int i = 0; i < 32; i += 8) {
    float v = tile[tx][ty + i];
    if constexpr (sizeof(T) == 2)
      out[(size_t)(c0 + ty + i) * R + (r0 + tx)] = (T)f2bf(v);
    else
      out[(size_t)(c0 + ty + i) * R + (r0 + tx)] = (T)v;
  }
}

// ---------------- bf16 MFMA GEMM (xw = emb @ W + b0), XCD-swizzled --------
template<bool OUT_BF16>
__launch_bounds__(256)
__global__ void gemm_bt(const unsigned short* __restrict__ A,
                        const unsigned short* __restrict__ BT,
                        const float* __restrict__ bias,
                        void* __restrict__ out, int N, int K) {
  __shared__ unsigned short As[128 * 32];
  __shared__ unsigned short Bs[128 * 32];
  const int tid = threadIdx.x;
  const int lane = tid & 63, wave = tid >> 6;
  const int wr = wave >> 1, wc = wave & 1;
  int nwg = gridDim.x * gridDim.y;
  int bid0 = blockIdx.y * gridDim.x + blockIdx.x;
  int q = nwg >> 3, r8 = nwg & 7;
  int xcd = bid0 & 7, idx = bid0 >> 3;
  int bid = (xcd < r8 ? xcd * (q + 1) : r8 * (q + 1) + (xcd - r8) * q) + idx;
  const int m0 = (bid / gridDim.x) * 128, n0 = (bid % gridDim.x) * 128;
  const int lr = lane & 15, lg = lane >> 4;
  float4v acc[4][4] = {};

  for (int k0 = 0; k0 < K; k0 += 32) {
    #pragma unroll
    for (int qq = 0; qq < 2; ++qq) {
      int byteoff = qq * 4096 + tid * 16;
      int rr = byteoff >> 6, cb = byteoff & 63;
      const char* ga = (const char*)A + ((size_t)(m0 + rr) * K + k0) * 2 + cb;
      const char* gb = (const char*)BT + ((size_t)(n0 + rr) * K + k0) * 2 + cb;
      char* la = (char*)As + qq * 4096 + wave * 1024;
      char* lb = (char*)Bs + qq * 4096 + wave * 1024;
      __builtin_amdgcn_global_load_lds((gas_u32*)ga, (las_u32*)la, 16, 0, 0);
      __builtin_amdgcn_global_load_lds((gas_u32*)gb, (las_u32*)lb, 16, 0, 0);
    }
    __syncthreads();
    short8v a[4], b[4];
    #pragma unroll
    for (int i = 0; i < 4; ++i)
      a[i] = *(const short8v*)((const char*)As + (wr * 64 + i * 16 + lr) * 64 + lg * 16);
    #pragma unroll
    for (int j = 0; j < 4; ++j)
      b[j] = *(const short8v*)((const char*)Bs + (wc * 64 + j * 16 + lr) * 64 + lg * 16);
    #pragma unroll
    for (int i = 0; i < 4; ++i) {
      #pragma unroll
      for (int j = 0; j < 4; ++j)
        acc[i][j] = __builtin_amdgcn_mfma_f32_16x16x32_bf16(a[i], b[j], acc[i][j], 0, 0, 0);
    }
    __syncthreads();
  }
  #pragma unroll
  for (int i = 0; i < 4; ++i) {
    int row = m0 + wr * 64 + i * 16 + lg * 4;
    #pragma unroll
    for (int j = 0; j < 4; ++j) {
      int col = n0 + wc * 64 + j * 16 + lr;
      float bv = bias[col];
      #pragma unroll
      for (int rr = 0; rr < 4; ++rr) {
        float v = acc[i][j][rr] + bv;
        if constexpr (OUT_BF16)
          ((unsigned short*)out)[(size_t)(row + rr) * N + col] = f2bf(v);
        else
          ((float*)out)[(size_t)(row + rr) * N + col] = v;
      }
    }
  }
}

// ---------------- fused persistent GRU + overlapped decoder -----------------
// 256 WGs x 512 threads (all co-resident): blocks 0..63 GRU, 64..255 decoder.
// GRU: R3 structure (4 groups x 16 WGs, data-as-flag Hex exchange) + per-step
//      release prog[grp][s] increment.
// Decoder: persistent 64x128 tiles; WG owns ct in {d, d+192}; sc-major order;
//      rare acquire on prog readiness, then global_load_lds staging + MFMA.
#define SENT 0xFFFFFFFFu
__launch_bounds__(512, 1)
__global__ void fused_kernel(const unsigned short* __restrict__ xw,   // [4096][1536] bf16
                             const float* __restrict__ UT,            // [1536][512] f32
                             const float* __restrict__ bvec,          // b[2][1536] f32
                             const unsigned short* __restrict__ WdT,  // [32000][512] bf16
                             const float* __restrict__ bd,            // [32000] f32
                             unsigned int* Hall,                      // [4096][256] u32 (bf16 pairs)
                             unsigned int* Hex,                       // [257][4][1024] u32, memset 0xFF
                             unsigned int* prog,                      // [4][256] u32, memset 0
                             float* out) {                            // [4096][32000] f32
  const int tid = threadIdx.x;
  const int lane = tid & 63, wave = tid >> 6;
  const int lr = lane & 15, lg = lane >> 4;
  __shared__ __align__(16) char smem[12288];

  if (blockIdx.x < GRU_WGS) {
    // ================= GRU role =================
    __builtin_amdgcn_s_setprio(1);
    unsigned short* h_lds = (unsigned short*)smem;        // 4KB, swizzled
    float (*red)[100] = (float(*)[100])(smem + 4096);     // 1.6KB
    const int w = blockIdx.x;
    const int grp = w >> 4;          // batches 4*grp .. 4*grp+3
    const int wq = w & 15;           // h-dims 32*wq .. 32*wq+32

    // one-time: U slice -> VGPR B-fragments (waves 0..5)
    short8v Bf[16];
    if (wave < 6) {
      int c = wave * 16 + lr;                      // 0..95
      int g = c >> 5, dloc = c & 31;
      const float* up = UT + (size_t)(g * 512 + 32 * wq + dloc) * 512 + lg * 8;
      #pragma unroll
      for (int kk = 0; kk < 16; ++kk) {
        float4 v0 = *(const float4*)(up + kk * 32);
        float4 v1 = *(const float4*)(up + kk * 32 + 4);
        short8v t;
        t[0] = (short)f2bf(v0.x); t[1] = (short)f2bf(v0.y);
        t[2] = (short)f2bf(v0.z); t[3] = (short)f2bf(v0.w);
        t[4] = (short)f2bf(v1.x); t[5] = (short)f2bf(v1.y);
        t[6] = (short)f2bf(v1.z); t[7] = (short)f2bf(v1.w);
        Bf[kk] = t;
      }
    }
    for (int idx = tid; idx < 256; idx += 512)
      reinterpret_cast<uint4*>(h_lds)[idx] = make_uint4(0, 0, 0, 0);

    // gate-thread constants (tid < 64): (b_loc, dim-pair dp)
    float h0 = 0.f, h1 = 0.f;
    float bz0 = 0, bz1 = 0, br0 = 0, br1 = 0, bh0 = 0, bh1 = 0;
    const int b_loc = tid >> 4, dp = tid & 15;
    const unsigned int* xp = nullptr;
    if (tid < 64) {
      const float* brec = bvec + 1536;
      int d = 32 * wq + 2 * dp;
      int b = grp * 4 + b_loc;
      bz0 = brec[d];        bz1 = brec[d + 1];
      br0 = brec[512 + d];  br1 = brec[513 + d];
      bh0 = brec[1024 + d]; bh1 = brec[1025 + d];
      xp = (const unsigned int*)xw + ((size_t)(b * 256) * 1536 + d) / 2;
    }
    const int pb = tid >> 6;                       // b_loc of polled words (tid<256)
    const bool own = ((tid >> 2) & 15) == wq;
    __syncthreads();

    for (int s = 0; s < 256; ++s) {
      unsigned int xzw = 0, xrw = 0, xhw = 0;
      if (tid < 64) { xzw = xp[0]; xrw = xp[256]; xhw = xp[512]; xp += 768; }

      if (s > 0 && tid < 256 && !own) {
        const unsigned int* src = Hex + ((size_t)s * 4 + grp) * 1024 + tid * 4;
        unsigned int vv[4];
        #pragma unroll
        for (int i = 0; i < 4; ++i)
          vv[i] = __hip_atomic_load(&src[i], __ATOMIC_RELAXED, __HIP_MEMORY_SCOPE_AGENT);
        unsigned int pend = 0xF;
        while (pend) {
          unsigned int np = 0;
          #pragma unroll
          for (int i = 0; i < 4; ++i) if (pend & (1u << i)) {
            if (vv[i] != SENT) {
              int dpp = (tid & 63) * 4 + i;
              *(unsigned int*)((char*)h_lds + ((pb * 1024 + dpp * 4) ^ (pb << 4))) = vv[i];
            } else np |= 1u << i;
          }
          pend = np;
          if (pend) {
            __builtin_amdgcn_s_sleep(1);
            #pragma unroll
            for (int i = 0; i < 4; ++i) if (pend & (1u << i))
              vv[i] = __hip_atomic_load(&src[i], __ATOMIC_RELAXED, __HIP_MEMORY_SCOPE_AGENT);
          }
        }
      }
      __syncthreads();

      // rec = h(4x512) @ U_slice : waves 0..5, 16 cols each
      if (wave < 6) {
        float4v acc0 = {}, acc1 = {};
        #pragma unroll
        for (int kk = 0; kk < 16; ++kk) {
          int byteoff = ((lr & 3) * 1024 + kk * 64 + lg * 16) ^ ((lr & 3) << 4);
          short8v a = *(const short8v*)((const char*)h_lds + byteoff);
          if (kk & 1) acc1 = __builtin_amdgcn_mfma_f32_16x16x32_bf16(a, Bf[kk], acc1, 0, 0, 0);
          else        acc0 = __builtin_amdgcn_mfma_f32_16x16x32_bf16(a, Bf[kk], acc0, 0, 0, 0);
        }
        if (lg == 0) {
          int c = wave * 16 + lr;
          #pragma unroll
          for (int rr = 0; rr < 4; ++rr)
            red[rr][c] = acc0[rr] + acc1[rr];
        }
      }
      __syncthreads();

      // gates: 64 threads, each owns (b_loc, dims 2dp, 2dp+1)
      if (tid < 64) {
        float rz0 = red[b_loc][2 * dp],      rz1 = red[b_loc][2 * dp + 1];
        float rr0 = red[b_loc][32 + 2 * dp], rr1 = red[b_loc][33 + 2 * dp];
        float rh0 = red[b_loc][64 + 2 * dp], rh1 = red[b_loc][65 + 2 * dp];
        float xz0 = bf2f((unsigned short)(xzw & 0xffff)), xz1 = bf2f((unsigned short)(xzw >> 16));
        float xr0 = bf2f((unsigned short)(xrw & 0xffff)), xr1 = bf2f((unsigned short)(xrw >> 16));
        float xh0 = bf2f((unsigned short)(xhw & 0xffff)), xh1 = bf2f((unsigned short)(xhw >> 16));
        float z0 = 1.f / (1.f + __expf(-(xz0 + rz0 + bz0)));
        float z1 = 1.f / (1.f + __expf(-(xz1 + rz1 + bz1)));
        float r0 = 1.f / (1.f + __expf(-(xr0 + rr0 + br0)));
        float r1 = 1.f / (1.f + __expf(-(xr1 + rr1 + br1)));
        float hh0 = fast_tanh(xh0 + r0 * (rh0 + bh0));
        float hh1 = fast_tanh(xh1 + r1 * (rh1 + bh1));
        h0 = z0 * h0 + (1.f - z0) * hh0;
        h1 = z1 * h1 + (1.f - z1) * hh1;
        unsigned int pack = (unsigned int)f2bf(h0) | ((unsigned int)f2bf(h1) << 16);
        int dpp = wq * 16 + dp;
        __hip_atomic_store(&Hex[((size_t)(s + 1) * 4 + grp) * 1024 + b_loc * 256 + dpp], pack,
                           __ATOMIC_RELAXED, __HIP_MEMORY_SCOPE_AGENT);
        *(unsigned int*)((char*)h_lds + ((b_loc * 1024 + dpp * 4) ^ (b_loc << 4))) = pack;
        __hip_atomic_store(&Hall[(size_t)((grp * 4 + b_loc) * 256 + s) * 256 + dpp], pack,
                           __ATOMIC_RELAXED, __HIP_MEMORY_SCOPE_AGENT);
        // publish step s of this WG (release covers whole wave's stores)
        if (tid == 0)
          __hip_atomic_fetch_add(&prog[grp * 256 + s], 1u,
                                 __ATOMIC_RELEASE, __HIP_MEMORY_SCOPE_AGENT);
      }
      // no third barrier (disjoint LDS words; mfma reads gated by next sync)
    }
  } else {
    // ================= decoder role =================
    unsigned short* As = (unsigned short*)smem;            // 64x32 bf16, 4KB
    unsigned short* Bs = (unsigned short*)(smem + 4096);   // 128x32 bf16, 8KB
    const int d = blockIdx.x - GRU_WGS;                    // 0..191
    const int wr = wave >> 2, wc = wave & 3;

    for (int sc = 0; sc < 4; ++sc) {
      const int s_need = sc * 64 + 63;
      unsigned ready = 0;                                  // bit g: prog confirmed
      for (int ct = d; ct < NCT; ct += DEC_WGS) {
        const int n0 = ct * 128;
        for (int b = 0; b < NB; ++b) {
          const int g = b >> 2;
          if (!(ready & (1u << g))) {
            if (tid == 0) {
              const unsigned int* pp = &prog[g * 256 + s_need];
              while (__hip_atomic_load(pp, __ATOMIC_RELAXED, __HIP_MEMORY_SCOPE_AGENT) < 16u)
                __builtin_amdgcn_s_sleep(8);
              (void)__hip_atomic_load(pp, __ATOMIC_ACQUIRE, __HIP_MEMORY_SCOPE_AGENT);
            }
            __syncthreads();
            ready |= 1u << g;
          }
          const int m0 = b * 256 + sc * 64;
          float4v acc[2][2] = {};
          for (int k0 = 0; k0 < NH; k0 += 32) {
            if (tid < 256) {
              #pragma unroll
              for (int qq = 0; qq < 2; ++qq) {
                int off = qq * 4096 + tid * 16;
                int row = off >> 6, cb = off & 63;
                const char* gb = (const char*)WdT + (size_t)(n0 + row) * 1024 + k0 * 2 + cb;
                char* lb = (char*)Bs + qq * 4096 + wave * 1024;
                __builtin_amdgcn_global_load_lds((gas_u32*)gb, (las_u32*)lb, 16, 0, 0);
              }
            } else {
              int off = (tid - 256) * 16;
              int row = off >> 6, cb = off & 63;
              const char* ga = (const char*)Hall + (size_t)(m0 + row) * 1024 + k0 * 2 + cb;
              char* la = (char*)As + (wave - 4) * 1024;
              __builtin_amdgcn_global_load_lds((gas_u32*)ga, (las_u32*)la, 16, 0, 0);
            }
            __syncthreads();
            short8v a[2], bb[2];
            #pragma unroll
            for (int i = 0; i < 2; ++i)
              a[i] = *(const short8v*)((const char*)As + (wr * 32 + i * 16 + lr) * 64 + lg * 16);
            #pragma unroll
            for (int j = 0; j < 2; ++j)
              bb[j] = *(const short8v*)((const char*)Bs + (wc * 32 + j * 16 + lr) * 64 + lg * 16);
            #pragma unroll
            for (int i = 0; i < 2; ++i) {
              #pragma unroll
              for (int j = 0; j < 2; ++j)
                acc[i][j] = __builtin_amdgcn_mfma_f32_16x16x32_bf16(a[i], bb[j], acc[i][j], 0, 0, 0);
            }
            __syncthreads();
          }
          #pragma unroll
          for (int i = 0; i < 2; ++i) {
            int row = m0 + wr * 32 + i * 16 + lg * 4;
            #pragma unroll
            for (int j = 0; j < 2; ++j) {
              int col = n0 + wc * 32 + j * 16 + lr;
              float bv = bd[col];
              #pragma unroll
              for (int rr = 0; rr < 4; ++rr)
                out[(size_t)(row + rr) * NV + col] = acc[i][j][rr] + bv;
            }
          }
        }
      }
    }
  }
}

// ---------------- launch ----------------
extern "C" void kernel_launch(void* const* d_in, const int* in_sizes, int n_in,
                              void* d_out, int out_size, void* d_ws, size_t ws_size,
                              hipStream_t stream) {
  const int*   x  = (const int*)d_in[0];
  const float* E  = (const float*)d_in[1];
  const float* W  = (const float*)d_in[2];
  const float* U  = (const float*)d_in[3];
  const float* bv = (const float*)d_in[4];
  const float* Wd = (const float*)d_in[5];
  const float* bd = (const float*)d_in[6];
  float* out = (float*)d_out;

  char* ws = (char*)d_ws;
  size_t off = 0;
  auto alloc = [&](size_t bytes) -> void* {
    void* p = ws + off;
    off = (off + bytes + 255) & ~(size_t)255;
    return p;
  };
  unsigned short* Aemb = (unsigned short*)alloc((size_t)NM * NE * 2);
  unsigned short* WT   = (unsigned short*)alloc((size_t)N3H * NE * 2);
  float*          UT   = (float*)alloc((size_t)N3H * NH * 4);
  unsigned short* xwb  = (unsigned short*)alloc((size_t)NM * N3H * 2);
  unsigned short* WdT  = (unsigned short*)alloc((size_t)NV * NH * 2);
  unsigned int*   Hall = (unsigned int*)alloc((size_t)NM * NH * 2);
  unsigned int*   Hex  = (unsigned int*)alloc((size_t)257 * 4096 * 4);
  unsigned int*   prog = (unsigned int*)alloc((size_t)4 * 256 * 4);

  hipMemsetAsync(Hex, 0xFF, (size_t)257 * 4096 * 4, stream);
  hipMemsetAsync(prog, 0, (size_t)4 * 256 * 4, stream);

  gather_emb<<<NM / 4, 256, 0, stream>>>(x, E, Aemb);
  transpose_conv<unsigned short><<<dim3(N3H / 32, NE / 32), dim3(32, 8), 0, stream>>>(W,  WT,  NE, N3H);
  transpose_conv<unsigned short><<<dim3(NV / 32,  NH / 32), dim3(32, 8), 0, stream>>>(Wd, WdT, NH, NV);
  transpose_conv<float>         <<<dim3(N3H / 32, NH / 32), dim3(32, 8), 0, stream>>>(U,  UT,  NH, N3H);

  gemm_bt<true><<<dim3(N3H / 128, NM / 128), 256, 0, stream>>>(Aemb, WT, bv, xwb, N3H, NE);

  fused_kernel<<<GRU_WGS + DEC_WGS, 512, 0, stream>>>(xwb, UT, bv, WdT, bd,
                                                      Hall, Hex, prog, out);
}

// Round 5
// 1074.752 us; speedup vs baseline: 1.4336x; 1.4336x over previous
//
#include <hip/hip_runtime.h>
#include <hip/hip_bf16.h>
#include <stdint.h>
#include <stddef.h>

// ---------------- problem dims ----------------
#define NB 16
#define NS 256
#define NH 512
#define NE 256
#define NV 32000
#define NM (NB*NS)        // 4096 flattened rows, m = b*256 + s
#define N3H 1536
#define GRU_WGS 64
#define DEC_WGS 448
#define NCT 250           // 32000 / 128 decoder col-tiles
#define TILES_PER_SC 2000 // 250 ct * 8 bp
#define NTILES 8000

typedef __attribute__((ext_vector_type(8))) short short8v;
typedef __attribute__((ext_vector_type(4))) float float4v;
typedef __attribute__((address_space(1))) const unsigned int gas_u32;
typedef __attribute__((address_space(3))) unsigned int las_u32;

static __device__ __forceinline__ unsigned short f2bf(float f) {
  __hip_bfloat16 h = __float2bfloat16(f);
  return *reinterpret_cast<unsigned short*>(&h);
}
static __device__ __forceinline__ float bf2f(unsigned short u) {
  union { unsigned int u; float f; } c;
  c.u = ((unsigned int)u) << 16;
  return c.f;
}
static __device__ __forceinline__ float fast_tanh(float x) {
  float t = __expf(2.f * x);
  return (t - 1.f) / (t + 1.f);
}

// ---------------- embedding gather + convert to bf16 ----------------
__global__ void gather_emb(const int* __restrict__ x, const float* __restrict__ E,
                           unsigned short* __restrict__ A) {
  int m = blockIdx.x * 4 + (threadIdx.x >> 6);
  int lane = threadIdx.x & 63;
  int t = x[m];
  float4 v = reinterpret_cast<const float4*>(E + (size_t)t * NE)[lane];
  ushort4 o = make_ushort4(f2bf(v.x), f2bf(v.y), f2bf(v.z), f2bf(v.w));
  reinterpret_cast<ushort4*>(A + (size_t)m * NE)[lane] = o;
}

// ---------------- tiled transpose, f32 in -> (bf16|f32) out ----------------
template<typename T>
__global__ void transpose_conv(const float* __restrict__ in, T* __restrict__ out,
                               int R, int C) {
  __shared__ float tile[32][33];
  int c0 = blockIdx.x * 32, r0 = blockIdx.y * 32;
  int tx = threadIdx.x, ty = threadIdx.y;
  #pragma unroll
  for (int i = 0; i < 32; i += 8)
    tile[ty + i][tx] = in[(size_t)(r0 + ty + i) * C + (c0 + tx)];
  __syncthreads();
  #pragma unroll
  for (int i = 0; i < 32; i += 8) {
    float v = tile[tx][ty + i];
    if constexpr (sizeof(T) == 2)
      out[(size_t)(c0 + ty + i) * R + (r0 + tx)] = (T)f2bf(v);
    else
      out[(size_t)(c0 + ty + i) * R + (r0 + tx)] = (T)v;
  }
}

// ---------------- bf16 MFMA GEMM (xw = emb @ W + b0), XCD-swizzled --------
template<bool OUT_BF16>
__launch_bounds__(256)
__global__ void gemm_bt(const unsigned short* __restrict__ A,
                        const unsigned short* __restrict__ BT,
                        const float* __restrict__ bias,
                        void* __restrict__ out, int N, int K) {
  __shared__ unsigned short As[128 * 32];
  __shared__ unsigned short Bs[128 * 32];
  const int tid = threadIdx.x;
  const int lane = tid & 63, wave = tid >> 6;
  const int wr = wave >> 1, wc = wave & 1;
  int nwg = gridDim.x * gridDim.y;
  int bid0 = blockIdx.y * gridDim.x + blockIdx.x;
  int q = nwg >> 3, r8 = nwg & 7;
  int xcd = bid0 & 7, idx = bid0 >> 3;
  int bid = (xcd < r8 ? xcd * (q + 1) : r8 * (q + 1) + (xcd - r8) * q) + idx;
  const int m0 = (bid / gridDim.x) * 128, n0 = (bid % gridDim.x) * 128;
  const int lr = lane & 15, lg = lane >> 4;
  float4v acc[4][4] = {};

  for (int k0 = 0; k0 < K; k0 += 32) {
    #pragma unroll
    for (int qq = 0; qq < 2; ++qq) {
      int byteoff = qq * 4096 + tid * 16;
      int rr = byteoff >> 6, cb = byteoff & 63;
      const char* ga = (const char*)A + ((size_t)(m0 + rr) * K + k0) * 2 + cb;
      const char* gb = (const char*)BT + ((size_t)(n0 + rr) * K + k0) * 2 + cb;
      char* la = (char*)As + qq * 4096 + wave * 1024;
      char* lb = (char*)Bs + qq * 4096 + wave * 1024;
      __builtin_amdgcn_global_load_lds((gas_u32*)ga, (las_u32*)la, 16, 0, 0);
      __builtin_amdgcn_global_load_lds((gas_u32*)gb, (las_u32*)lb, 16, 0, 0);
    }
    __syncthreads();
    short8v a[4], b[4];
    #pragma unroll
    for (int i = 0; i < 4; ++i)
      a[i] = *(const short8v*)((const char*)As + (wr * 64 + i * 16 + lr) * 64 + lg * 16);
    #pragma unroll
    for (int j = 0; j < 4; ++j)
      b[j] = *(const short8v*)((const char*)Bs + (wc * 64 + j * 16 + lr) * 64 + lg * 16);
    #pragma unroll
    for (int i = 0; i < 4; ++i) {
      #pragma unroll
      for (int j = 0; j < 4; ++j)
        acc[i][j] = __builtin_amdgcn_mfma_f32_16x16x32_bf16(a[i], b[j], acc[i][j], 0, 0, 0);
    }
    __syncthreads();
  }
  #pragma unroll
  for (int i = 0; i < 4; ++i) {
    int row = m0 + wr * 64 + i * 16 + lg * 4;
    #pragma unroll
    for (int j = 0; j < 4; ++j) {
      int col = n0 + wc * 64 + j * 16 + lr;
      float bv = bias[col];
      #pragma unroll
      for (int rr = 0; rr < 4; ++rr) {
        float v = acc[i][j][rr] + bv;
        if constexpr (OUT_BF16)
          ((unsigned short*)out)[(size_t)(row + rr) * N + col] = f2bf(v);
        else
          ((float*)out)[(size_t)(row + rr) * N + col] = v;
      }
    }
  }
}

// ---------------- fused persistent GRU + overlapped decoder -----------------
// 512 WGs x 512 threads. Blocks 0..63: GRU (R3 structure + prog release).
// Blocks 64..511: decoder, dynamic tile queue, 128x128 tiles, m-rows =
// 2 batches x 64 s (readiness quantum = 64 GRU steps), 2 WGs/CU for TLP.
#define SENT 0xFFFFFFFFu
__launch_bounds__(512, 4)
__global__ void fused_kernel(const unsigned short* __restrict__ xw,   // [4096][1536] bf16
                             const float* __restrict__ UT,            // [1536][512] f32
                             const float* __restrict__ bvec,          // b[2][1536] f32
                             const unsigned short* __restrict__ WdT,  // [32000][512] bf16
                             const float* __restrict__ bd,            // [32000] f32
                             unsigned int* Hall,                      // [4096][256] u32 (bf16 pairs)
                             unsigned int* Hex,                       // [257][4][1024] u32, memset 0xFF
                             unsigned int* prog,                      // [4][256] u32, memset 0
                             unsigned int* ctr,                       // [1] u32, memset 0
                             float* out) {                            // [4096][32000] f32
  const int tid = threadIdx.x;
  const int lane = tid & 63, wave = tid >> 6;
  const int lr = lane & 15, lg = lane >> 4;
  __shared__ __align__(16) char smem[16400];

  if (blockIdx.x < GRU_WGS) {
    // ================= GRU role =================
    __builtin_amdgcn_s_setprio(1);
    unsigned short* h_lds = (unsigned short*)smem;        // 4KB, swizzled
    float (*red)[100] = (float(*)[100])(smem + 4096);     // 1.6KB
    const int w = blockIdx.x;
    const int grp = w >> 4;          // batches 4*grp .. 4*grp+3
    const int wq = w & 15;           // h-dims 32*wq .. 32*wq+32

    // one-time: U slice -> VGPR B-fragments (waves 0..5)
    short8v Bf[16];
    if (wave < 6) {
      int c = wave * 16 + lr;                      // 0..95
      int g = c >> 5, dloc = c & 31;
      const float* up = UT + (size_t)(g * 512 + 32 * wq + dloc) * 512 + lg * 8;
      #pragma unroll
      for (int kk = 0; kk < 16; ++kk) {
        float4 v0 = *(const float4*)(up + kk * 32);
        float4 v1 = *(const float4*)(up + kk * 32 + 4);
        short8v t;
        t[0] = (short)f2bf(v0.x); t[1] = (short)f2bf(v0.y);
        t[2] = (short)f2bf(v0.z); t[3] = (short)f2bf(v0.w);
        t[4] = (short)f2bf(v1.x); t[5] = (short)f2bf(v1.y);
        t[6] = (short)f2bf(v1.z); t[7] = (short)f2bf(v1.w);
        Bf[kk] = t;
      }
    }
    for (int idx = tid; idx < 256; idx += 512)
      reinterpret_cast<uint4*>(h_lds)[idx] = make_uint4(0, 0, 0, 0);

    // gate-thread constants (tid < 64 = wave 0): (b_loc, dim-pair dp)
    float h0 = 0.f, h1 = 0.f;
    float bz0 = 0, bz1 = 0, br0 = 0, br1 = 0, bh0 = 0, bh1 = 0;
    const int b_loc = tid >> 4, dp = tid & 15;
    const unsigned int* xp = nullptr;
    if (tid < 64) {
      const float* brec = bvec + 1536;
      int d = 32 * wq + 2 * dp;
      int b = grp * 4 + b_loc;
      bz0 = brec[d];        bz1 = brec[d + 1];
      br0 = brec[512 + d];  br1 = brec[513 + d];
      bh0 = brec[1024 + d]; bh1 = brec[1025 + d];
      xp = (const unsigned int*)xw + ((size_t)(b * 256) * 1536 + d) / 2;
    }
    const int pb = tid >> 6;                       // b_loc of polled words (tid<256)
    const bool own = ((tid >> 2) & 15) == wq;
    __syncthreads();

    for (int s = 0; s < 256; ++s) {
      unsigned int xzw = 0, xrw = 0, xhw = 0;
      if (tid < 64) { xzw = xp[0]; xrw = xp[256]; xhw = xp[512]; xp += 768; }

      if (s > 0 && tid < 256 && !own) {
        const unsigned long long* src =
            (const unsigned long long*)(Hex + ((size_t)s * 4 + grp) * 1024 + tid * 4);
        unsigned long long v0 = __hip_atomic_load(&src[0], __ATOMIC_RELAXED, __HIP_MEMORY_SCOPE_AGENT);
        unsigned long long v1 = __hip_atomic_load(&src[1], __ATOMIC_RELAXED, __HIP_MEMORY_SCOPE_AGENT);
        unsigned int pend = 3;
        while (pend) {
          unsigned int np = 0;
          if (pend & 1) {
            if ((unsigned int)v0 != SENT && (unsigned int)(v0 >> 32) != SENT) {
              int dpp = (tid & 63) * 4;
              *(unsigned long long*)((char*)h_lds + ((pb * 1024 + dpp * 4) ^ (pb << 4))) = v0;
            } else np |= 1;
          }
          if (pend & 2) {
            if ((unsigned int)v1 != SENT && (unsigned int)(v1 >> 32) != SENT) {
              int dpp = (tid & 63) * 4 + 2;
              *(unsigned long long*)((char*)h_lds + ((pb * 1024 + dpp * 4) ^ (pb << 4))) = v1;
            } else np |= 2;
          }
          pend = np;
          if (pend) {
            __builtin_amdgcn_s_sleep(1);
            if (pend & 1) v0 = __hip_atomic_load(&src[0], __ATOMIC_RELAXED, __HIP_MEMORY_SCOPE_AGENT);
            if (pend & 2) v1 = __hip_atomic_load(&src[1], __ATOMIC_RELAXED, __HIP_MEMORY_SCOPE_AGENT);
          }
        }
      }
      __syncthreads();

      // rec = h(4x512) @ U_slice : waves 0..5, 16 cols each
      if (wave < 6) {
        float4v acc0 = {}, acc1 = {};
        #pragma unroll
        for (int kk = 0; kk < 16; ++kk) {
          int byteoff = ((lr & 3) * 1024 + kk * 64 + lg * 16) ^ ((lr & 3) << 4);
          short8v a = *(const short8v*)((const char*)h_lds + byteoff);
          if (kk & 1) acc1 = __builtin_amdgcn_mfma_f32_16x16x32_bf16(a, Bf[kk], acc1, 0, 0, 0);
          else        acc0 = __builtin_amdgcn_mfma_f32_16x16x32_bf16(a, Bf[kk], acc0, 0, 0, 0);
        }
        if (lg == 0) {
          int c = wave * 16 + lr;
          #pragma unroll
          for (int rr = 0; rr < 4; ++rr)
            red[rr][c] = acc0[rr] + acc1[rr];
        }
      }
      __syncthreads();

      // gates: 64 threads (wave 0), each owns (b_loc, dims 2dp, 2dp+1)
      if (tid < 64) {
        float rz0 = red[b_loc][2 * dp],      rz1 = red[b_loc][2 * dp + 1];
        float rr0 = red[b_loc][32 + 2 * dp], rr1 = red[b_loc][33 + 2 * dp];
        float rh0 = red[b_loc][64 + 2 * dp], rh1 = red[b_loc][65 + 2 * dp];
        float xz0 = bf2f((unsigned short)(xzw & 0xffff)), xz1 = bf2f((unsigned short)(xzw >> 16));
        float xr0 = bf2f((unsigned short)(xrw & 0xffff)), xr1 = bf2f((unsigned short)(xrw >> 16));
        float xh0 = bf2f((unsigned short)(xhw & 0xffff)), xh1 = bf2f((unsigned short)(xhw >> 16));
        float z0 = 1.f / (1.f + __expf(-(xz0 + rz0 + bz0)));
        float z1 = 1.f / (1.f + __expf(-(xz1 + rz1 + bz1)));
        float r0 = 1.f / (1.f + __expf(-(xr0 + rr0 + br0)));
        float r1 = 1.f / (1.f + __expf(-(xr1 + rr1 + br1)));
        float hh0 = fast_tanh(xh0 + r0 * (rh0 + bh0));
        float hh1 = fast_tanh(xh1 + r1 * (rh1 + bh1));
        h0 = z0 * h0 + (1.f - z0) * hh0;
        h1 = z1 * h1 + (1.f - z1) * hh1;
        unsigned int pack = (unsigned int)f2bf(h0) | ((unsigned int)f2bf(h1) << 16);
        int dpp = wq * 16 + dp;
        __hip_atomic_store(&Hex[((size_t)(s + 1) * 4 + grp) * 1024 + b_loc * 256 + dpp], pack,
                           __ATOMIC_RELAXED, __HIP_MEMORY_SCOPE_AGENT);
        *(unsigned int*)((char*)h_lds + ((b_loc * 1024 + dpp * 4) ^ (b_loc << 4))) = pack;
        __hip_atomic_store(&Hall[(size_t)((grp * 4 + b_loc) * 256 + s) * 256 + dpp], pack,
                           __ATOMIC_RELAXED, __HIP_MEMORY_SCOPE_AGENT);
        // release: wave-level vmcnt drain covers all wave-0 stores above
        if (tid == 0)
          __hip_atomic_fetch_add(&prog[grp * 256 + s], 1u,
                                 __ATOMIC_RELEASE, __HIP_MEMORY_SCOPE_AGENT);
      }
      // no third barrier (disjoint LDS words; mfma reads gated by next sync)
    }
  } else {
    // ================= decoder role =================
    unsigned short* As = (unsigned short*)smem;            // 128x32 bf16, 8KB
    unsigned short* Bs = (unsigned short*)(smem + 8192);   // 128x32 bf16, 8KB
    unsigned int* tslot = (unsigned int*)(smem + 16384);
    const int wr = wave >> 2, wc = wave & 3;               // 2 x 4 wave grid
    int last_sc = -1;
    unsigned gmask = 0;

    for (;;) {
      if (tid == 0)
        *tslot = __hip_atomic_fetch_add(ctr, 1u, __ATOMIC_RELAXED, __HIP_MEMORY_SCOPE_AGENT);
      __syncthreads();
      unsigned t = *tslot;
      if (t >= NTILES) break;
      const int sc = t / TILES_PER_SC;
      const int tt = t % TILES_PER_SC;
      const int ct = tt >> 3, bp = tt & 7;                 // batches 2bp, 2bp+1 (same group)
      const int grp = bp >> 1;
      const int n0 = ct * 128;

      if (sc != last_sc) { last_sc = sc; gmask = 0; }
      if (!(gmask & (1u << grp))) {
        if (tid == 0) {
          const unsigned int* pp = &prog[grp * 256 + sc * 64 + 63];
          while (__hip_atomic_load(pp, __ATOMIC_RELAXED, __HIP_MEMORY_SCOPE_AGENT) < 16u)
            __builtin_amdgcn_s_sleep(32);
          (void)__hip_atomic_load(pp, __ATOMIC_ACQUIRE, __HIP_MEMORY_SCOPE_AGENT);
        }
        __syncthreads();
        gmask |= 1u << grp;
      }

      float4v acc[4][2] = {};
      for (int k0 = 0; k0 < NH; k0 += 32) {
        if (tid < 256) {
          #pragma unroll
          for (int qq = 0; qq < 2; ++qq) {
            int off = qq * 4096 + tid * 16;
            int rloc = off >> 6, cb = off & 63;
            int m = (bp * 2 + (rloc >> 6)) * 256 + sc * 64 + (rloc & 63);
            const char* ga = (const char*)Hall + (size_t)m * 1024 + k0 * 2 + cb;
            char* la = (char*)As + qq * 4096 + wave * 1024;
            __builtin_amdgcn_global_load_lds((gas_u32*)ga, (las_u32*)la, 16, 0, 0);
          }
        } else {
          int t2 = tid - 256;
          #pragma unroll
          for (int qq = 0; qq < 2; ++qq) {
            int off = qq * 4096 + t2 * 16;
            int rloc = off >> 6, cb = off & 63;
            const char* gb = (const char*)WdT + (size_t)(n0 + rloc) * 1024 + k0 * 2 + cb;
            char* lb = (char*)Bs + qq * 4096 + (wave - 4) * 1024;
            __builtin_amdgcn_global_load_lds((gas_u32*)gb, (las_u32*)lb, 16, 0, 0);
          }
        }
        __syncthreads();
        short8v a[4], b2[2];
        #pragma unroll
        for (int i = 0; i < 4; ++i)
          a[i] = *(const short8v*)((const char*)As + (wr * 64 + i * 16 + lr) * 64 + lg * 16);
        #pragma unroll
        for (int j = 0; j < 2; ++j)
          b2[j] = *(const short8v*)((const char*)Bs + (wc * 32 + j * 16 + lr) * 64 + lg * 16);
        #pragma unroll
        for (int i = 0; i < 4; ++i) {
          #pragma unroll
          for (int j = 0; j < 2; ++j)
            acc[i][j] = __builtin_amdgcn_mfma_f32_16x16x32_bf16(a[i], b2[j], acc[i][j], 0, 0, 0);
        }
        __syncthreads();
      }
      #pragma unroll
      for (int i = 0; i < 4; ++i) {
        int rbase = wr * 64 + i * 16 + lg * 4;
        #pragma unroll
        for (int j = 0; j < 2; ++j) {
          int col = n0 + wc * 32 + j * 16 + lr;
          float bv = bd[col];
          #pragma unroll
          for (int rr = 0; rr < 4; ++rr) {
            int rloc = rbase + rr;
            int m = (bp * 2 + (rloc >> 6)) * 256 + sc * 64 + (rloc & 63);
            out[(size_t)m * NV + col] = acc[i][j][rr] + bv;
          }
        }
      }
    }
  }
}

// ---------------- launch ----------------
extern "C" void kernel_launch(void* const* d_in, const int* in_sizes, int n_in,
                              void* d_out, int out_size, void* d_ws, size_t ws_size,
                              hipStream_t stream) {
  const int*   x  = (const int*)d_in[0];
  const float* E  = (const float*)d_in[1];
  const float* W  = (const float*)d_in[2];
  const float* U  = (const float*)d_in[3];
  const float* bv = (const float*)d_in[4];
  const float* Wd = (const float*)d_in[5];
  const float* bd = (const float*)d_in[6];
  float* out = (float*)d_out;

  char* ws = (char*)d_ws;
  size_t off = 0;
  auto alloc = [&](size_t bytes) -> void* {
    void* p = ws + off;
    off = (off + bytes + 255) & ~(size_t)255;
    return p;
  };
  unsigned short* Aemb = (unsigned short*)alloc((size_t)NM * NE * 2);
  unsigned short* WT   = (unsigned short*)alloc((size_t)N3H * NE * 2);
  float*          UT   = (float*)alloc((size_t)N3H * NH * 4);
  unsigned short* xwb  = (unsigned short*)alloc((size_t)NM * N3H * 2);
  unsigned short* WdT  = (unsigned short*)alloc((size_t)NV * NH * 2);
  unsigned int*   Hall = (unsigned int*)alloc((size_t)NM * NH * 2);
  unsigned int*   Hex  = (unsigned int*)alloc((size_t)257 * 4096 * 4);
  unsigned int*   prog = (unsigned int*)alloc((size_t)4 * 256 * 4);
  unsigned int*   ctr  = (unsigned int*)alloc(256);

  hipMemsetAsync(Hex, 0xFF, (size_t)257 * 4096 * 4, stream);
  hipMemsetAsync(prog, 0, (size_t)4 * 256 * 4, stream);
  hipMemsetAsync(ctr, 0, 256, stream);

  gather_emb<<<NM / 4, 256, 0, stream>>>(x, E, Aemb);
  transpose_conv<unsigned short><<<dim3(N3H / 32, NE / 32), dim3(32, 8), 0, stream>>>(W,  WT,  NE, N3H);
  transpose_conv<unsigned short><<<dim3(NV / 32,  NH / 32), dim3(32, 8), 0, stream>>>(Wd, WdT, NH, NV);
  transpose_conv<float>         <<<dim3(N3H / 32, NH / 32), dim3(32, 8), 0, stream>>>(U,  UT,  NH, N3H);

  gemm_bt<true><<<dim3(N3H / 128, NM / 128), 256, 0, stream>>>(Aemb, WT, bv, xwb, N3H, NE);

  fused_kernel<<<GRU_WGS + DEC_WGS, 512, 0, stream>>>(xwb, UT, bv, WdT, bd,
                                                      Hall, Hex, prog, ctr, out);
}

// Round 6
// 1028.996 us; speedup vs baseline: 1.4973x; 1.0445x over previous
//
#include <hip/hip_runtime.h>
#include <hip/hip_bf16.h>
#include <stdint.h>
#include <stddef.h>

// ---------------- problem dims ----------------
#define NB 16
#define NS 256
#define NH 512
#define NE 256
#define NV 32000
#define NM (NB*NS)        // 4096 flattened rows, m = b*256 + s
#define N3H 1536
#define GRU_WGS 64
#define DEC_WGS 192
#define TILES_PER_SC 500  // 250 ct * 2 bp
#define NTILES 8000       // 16 sc * 500

typedef __attribute__((ext_vector_type(8))) short short8v;
typedef __attribute__((ext_vector_type(4))) float float4v;
typedef __attribute__((address_space(1))) const unsigned int gas_u32;
typedef __attribute__((address_space(3))) unsigned int las_u32;

static __device__ __forceinline__ unsigned short f2bf(float f) {
  __hip_bfloat16 h = __float2bfloat16(f);
  return *reinterpret_cast<unsigned short*>(&h);
}
static __device__ __forceinline__ float bf2f(unsigned short u) {
  union { unsigned int u; float f; } c;
  c.u = ((unsigned int)u) << 16;
  return c.f;
}
static __device__ __forceinline__ float fast_tanh(float x) {
  float t = __expf(2.f * x);
  return (t - 1.f) / (t + 1.f);
}

// ---------------- embedding gather + convert to bf16 ----------------
__global__ void gather_emb(const int* __restrict__ x, const float* __restrict__ E,
                           unsigned short* __restrict__ A) {
  int m = blockIdx.x * 4 + (threadIdx.x >> 6);
  int lane = threadIdx.x & 63;
  int t = x[m];
  float4 v = reinterpret_cast<const float4*>(E + (size_t)t * NE)[lane];
  ushort4 o = make_ushort4(f2bf(v.x), f2bf(v.y), f2bf(v.z), f2bf(v.w));
  reinterpret_cast<ushort4*>(A + (size_t)m * NE)[lane] = o;
}

// ---------------- tiled transpose, f32 in -> (bf16|f32) out ----------------
template<typename T>
__global__ void transpose_conv(const float* __restrict__ in, T* __restrict__ out,
                               int R, int C) {
  __shared__ float tile[32][33];
  int c0 = blockIdx.x * 32, r0 = blockIdx.y * 32;
  int tx = threadIdx.x, ty = threadIdx.y;
  #pragma unroll
  for (int i = 0; i < 32; i += 8)
    tile[ty + i][tx] = in[(size_t)(r0 + ty + i) * C + (c0 + tx)];
  __syncthreads();
  #pragma unroll
  for (int i = 0; i < 32; i += 8) {
    float v = tile[tx][ty + i];
    if constexpr (sizeof(T) == 2)
      out[(size_t)(c0 + ty + i) * R + (r0 + tx)] = (T)f2bf(v);
    else
      out[(size_t)(c0 + ty + i) * R + (r0 + tx)] = (T)v;
  }
}

// ---------------- bf16 MFMA GEMM (xw = emb @ W + b0), XCD-swizzled --------
template<bool OUT_BF16>
__launch_bounds__(256)
__global__ void gemm_bt(const unsigned short* __restrict__ A,
                        const unsigned short* __restrict__ BT,
                        const float* __restrict__ bias,
                        void* __restrict__ out, int N, int K) {
  __shared__ unsigned short As[128 * 32];
  __shared__ unsigned short Bs[128 * 32];
  const int tid = threadIdx.x;
  const int lane = tid & 63, wave = tid >> 6;
  const int wr = wave >> 1, wc = wave & 1;
  int nwg = gridDim.x * gridDim.y;
  int bid0 = blockIdx.y * gridDim.x + blockIdx.x;
  int q = nwg >> 3, r8 = nwg & 7;
  int xcd = bid0 & 7, idx = bid0 >> 3;
  int bid = (xcd < r8 ? xcd * (q + 1) : r8 * (q + 1) + (xcd - r8) * q) + idx;
  const int m0 = (bid / gridDim.x) * 128, n0 = (bid % gridDim.x) * 128;
  const int lr = lane & 15, lg = lane >> 4;
  float4v acc[4][4] = {};

  for (int k0 = 0; k0 < K; k0 += 32) {
    #pragma unroll
    for (int qq = 0; qq < 2; ++qq) {
      int byteoff = qq * 4096 + tid * 16;
      int rr = byteoff >> 6, cb = byteoff & 63;
      const char* ga = (const char*)A + ((size_t)(m0 + rr) * K + k0) * 2 + cb;
      const char* gb = (const char*)BT + ((size_t)(n0 + rr) * K + k0) * 2 + cb;
      char* la = (char*)As + qq * 4096 + wave * 1024;
      char* lb = (char*)Bs + qq * 4096 + wave * 1024;
      __builtin_amdgcn_global_load_lds((gas_u32*)ga, (las_u32*)la, 16, 0, 0);
      __builtin_amdgcn_global_load_lds((gas_u32*)gb, (las_u32*)lb, 16, 0, 0);
    }
    __syncthreads();
    short8v a[4], b[4];
    #pragma unroll
    for (int i = 0; i < 4; ++i)
      a[i] = *(const short8v*)((const char*)As + (wr * 64 + i * 16 + lr) * 64 + lg * 16);
    #pragma unroll
    for (int j = 0; j < 4; ++j)
      b[j] = *(const short8v*)((const char*)Bs + (wc * 64 + j * 16 + lr) * 64 + lg * 16);
    #pragma unroll
    for (int i = 0; i < 4; ++i) {
      #pragma unroll
      for (int j = 0; j < 4; ++j)
        acc[i][j] = __builtin_amdgcn_mfma_f32_16x16x32_bf16(a[i], b[j], acc[i][j], 0, 0, 0);
    }
    __syncthreads();
  }
  #pragma unroll
  for (int i = 0; i < 4; ++i) {
    int row = m0 + wr * 64 + i * 16 + lg * 4;
    #pragma unroll
    for (int j = 0; j < 4; ++j) {
      int col = n0 + wc * 64 + j * 16 + lr;
      float bv = bias[col];
      #pragma unroll
      for (int rr = 0; rr < 4; ++rr) {
        float v = acc[i][j][rr] + bv;
        if constexpr (OUT_BF16)
          ((unsigned short*)out)[(size_t)(row + rr) * N + col] = f2bf(v);
        else
          ((float*)out)[(size_t)(row + rr) * N + col] = v;
      }
    }
  }
}

// ---------------- fused persistent GRU + overlapped decoder -----------------
// 256 WGs x 512 threads -> 1 WG/CU (breadth-first placement): GRU CUs dedicated.
// Blocks 0..63: GRU (R3 structure, u64 poll, prog release per step).
// Blocks 64..255: decoder. Phase 1: cooperative Wd->WdT transpose (agent-scope
// u32 stores) + release/acquire barrier among decoder WGs. Phase 2: dynamic
// tile queue, 128x128 tiles, m-rows = 8 batches x 16 s (16-step quanta).
#define SENT 0xFFFFFFFFu
__launch_bounds__(512)
__global__ void fused_kernel(const unsigned short* __restrict__ xw,   // [4096][1536] bf16
                             const float* __restrict__ UT,            // [1536][512] f32
                             const float* __restrict__ bvec,          // b[2][1536] f32
                             const float* __restrict__ Wd,            // [512][32000] f32
                             const float* __restrict__ bd,            // [32000] f32
                             unsigned int* WdTu,                      // [32000][256] u32 (bf16 pairs)
                             unsigned int* Hall,                      // [4096][256] u32 (bf16 pairs)
                             unsigned int* Hex,                       // [257][4][1024] u32, memset 0xFF
                             unsigned int* prog,                      // [4][256] u32, memset 0
                             unsigned int* ctr,                       // tile counter, memset 0
                             unsigned int* done,                      // transpose barrier, memset 0
                             float* out) {                            // [4096][32000] f32
  const int tid = threadIdx.x;
  const int lane = tid & 63, wave = tid >> 6;
  const int lr = lane & 15, lg = lane >> 4;
  __shared__ __align__(16) char smem[16400];

  if (blockIdx.x < GRU_WGS) {
    // ================= GRU role =================
    __builtin_amdgcn_s_setprio(1);
    unsigned short* h_lds = (unsigned short*)smem;        // 4KB, swizzled
    float (*red)[100] = (float(*)[100])(smem + 4096);     // 1.6KB
    const int w = blockIdx.x;
    const int grp = w >> 4;          // batches 4*grp .. 4*grp+3
    const int wq = w & 15;           // h-dims 32*wq .. 32*wq+32

    // one-time: U slice -> VGPR B-fragments (waves 0..5)
    short8v Bf[16];
    if (wave < 6) {
      int c = wave * 16 + lr;                      // 0..95
      int g = c >> 5, dloc = c & 31;
      const float* up = UT + (size_t)(g * 512 + 32 * wq + dloc) * 512 + lg * 8;
      #pragma unroll
      for (int kk = 0; kk < 16; ++kk) {
        float4 v0 = *(const float4*)(up + kk * 32);
        float4 v1 = *(const float4*)(up + kk * 32 + 4);
        short8v t;
        t[0] = (short)f2bf(v0.x); t[1] = (short)f2bf(v0.y);
        t[2] = (short)f2bf(v0.z); t[3] = (short)f2bf(v0.w);
        t[4] = (short)f2bf(v1.x); t[5] = (short)f2bf(v1.y);
        t[6] = (short)f2bf(v1.z); t[7] = (short)f2bf(v1.w);
        Bf[kk] = t;
      }
    }
    for (int idx = tid; idx < 256; idx += 512)
      reinterpret_cast<uint4*>(h_lds)[idx] = make_uint4(0, 0, 0, 0);

    // gate-thread constants (tid < 64 = wave 0): (b_loc, dim-pair dp)
    float h0 = 0.f, h1 = 0.f;
    float bz0 = 0, bz1 = 0, br0 = 0, br1 = 0, bh0 = 0, bh1 = 0;
    const int b_loc = tid >> 4, dp = tid & 15;
    const unsigned int* xp = nullptr;
    if (tid < 64) {
      const float* brec = bvec + 1536;
      int d = 32 * wq + 2 * dp;
      int b = grp * 4 + b_loc;
      bz0 = brec[d];        bz1 = brec[d + 1];
      br0 = brec[512 + d];  br1 = brec[513 + d];
      bh0 = brec[1024 + d]; bh1 = brec[1025 + d];
      xp = (const unsigned int*)xw + ((size_t)(b * 256) * 1536 + d) / 2;
    }
    const int pb = tid >> 6;                       // b_loc of polled words (tid<256)
    const bool own = ((tid >> 2) & 15) == wq;
    __syncthreads();

    for (int s = 0; s < 256; ++s) {
      unsigned int xzw = 0, xrw = 0, xhw = 0;
      if (tid < 64) { xzw = xp[0]; xrw = xp[256]; xhw = xp[512]; xp += 768; }

      if (s > 0 && tid < 256 && !own) {
        const unsigned long long* src =
            (const unsigned long long*)(Hex + ((size_t)s * 4 + grp) * 1024 + tid * 4);
        unsigned long long v0 = __hip_atomic_load(&src[0], __ATOMIC_RELAXED, __HIP_MEMORY_SCOPE_AGENT);
        unsigned long long v1 = __hip_atomic_load(&src[1], __ATOMIC_RELAXED, __HIP_MEMORY_SCOPE_AGENT);
        unsigned int pend = 3;
        while (pend) {
          unsigned int np = 0;
          if (pend & 1) {
            if ((unsigned int)v0 != SENT && (unsigned int)(v0 >> 32) != SENT) {
              int dpp = (tid & 63) * 4;
              *(unsigned long long*)((char*)h_lds + ((pb * 1024 + dpp * 4) ^ (pb << 4))) = v0;
            } else np |= 1;
          }
          if (pend & 2) {
            if ((unsigned int)v1 != SENT && (unsigned int)(v1 >> 32) != SENT) {
              int dpp = (tid & 63) * 4 + 2;
              *(unsigned long long*)((char*)h_lds + ((pb * 1024 + dpp * 4) ^ (pb << 4))) = v1;
            } else np |= 2;
          }
          pend = np;
          if (pend) {
            __builtin_amdgcn_s_sleep(1);
            if (pend & 1) v0 = __hip_atomic_load(&src[0], __ATOMIC_RELAXED, __HIP_MEMORY_SCOPE_AGENT);
            if (pend & 2) v1 = __hip_atomic_load(&src[1], __ATOMIC_RELAXED, __HIP_MEMORY_SCOPE_AGENT);
          }
        }
      }
      __syncthreads();

      // rec = h(4x512) @ U_slice : waves 0..5, 16 cols each
      if (wave < 6) {
        float4v acc0 = {}, acc1 = {};
        #pragma unroll
        for (int kk = 0; kk < 16; ++kk) {
          int byteoff = ((lr & 3) * 1024 + kk * 64 + lg * 16) ^ ((lr & 3) << 4);
          short8v a = *(const short8v*)((const char*)h_lds + byteoff);
          if (kk & 1) acc1 = __builtin_amdgcn_mfma_f32_16x16x32_bf16(a, Bf[kk], acc1, 0, 0, 0);
          else        acc0 = __builtin_amdgcn_mfma_f32_16x16x32_bf16(a, Bf[kk], acc0, 0, 0, 0);
        }
        if (lg == 0) {
          int c = wave * 16 + lr;
          #pragma unroll
          for (int rr = 0; rr < 4; ++rr)
            red[rr][c] = acc0[rr] + acc1[rr];
        }
      }
      __syncthreads();

      // gates: 64 threads (wave 0), each owns (b_loc, dims 2dp, 2dp+1)
      if (tid < 64) {
        float rz0 = red[b_loc][2 * dp],      rz1 = red[b_loc][2 * dp + 1];
        float rr0 = red[b_loc][32 + 2 * dp], rr1 = red[b_loc][33 + 2 * dp];
        float rh0 = red[b_loc][64 + 2 * dp], rh1 = red[b_loc][65 + 2 * dp];
        float xz0 = bf2f((unsigned short)(xzw & 0xffff)), xz1 = bf2f((unsigned short)(xzw >> 16));
        float xr0 = bf2f((unsigned short)(xrw & 0xffff)), xr1 = bf2f((unsigned short)(xrw >> 16));
        float xh0 = bf2f((unsigned short)(xhw & 0xffff)), xh1 = bf2f((unsigned short)(xhw >> 16));
        float z0 = 1.f / (1.f + __expf(-(xz0 + rz0 + bz0)));
        float z1 = 1.f / (1.f + __expf(-(xz1 + rz1 + bz1)));
        float r0 = 1.f / (1.f + __expf(-(xr0 + rr0 + br0)));
        float r1 = 1.f / (1.f + __expf(-(xr1 + rr1 + br1)));
        float hh0 = fast_tanh(xh0 + r0 * (rh0 + bh0));
        float hh1 = fast_tanh(xh1 + r1 * (rh1 + bh1));
        h0 = z0 * h0 + (1.f - z0) * hh0;
        h1 = z1 * h1 + (1.f - z1) * hh1;
        unsigned int pack = (unsigned int)f2bf(h0) | ((unsigned int)f2bf(h1) << 16);
        int dpp = wq * 16 + dp;
        __hip_atomic_store(&Hex[((size_t)(s + 1) * 4 + grp) * 1024 + b_loc * 256 + dpp], pack,
                           __ATOMIC_RELAXED, __HIP_MEMORY_SCOPE_AGENT);
        *(unsigned int*)((char*)h_lds + ((b_loc * 1024 + dpp * 4) ^ (b_loc << 4))) = pack;
        __hip_atomic_store(&Hall[(size_t)((grp * 4 + b_loc) * 256 + s) * 256 + dpp], pack,
                           __ATOMIC_RELAXED, __HIP_MEMORY_SCOPE_AGENT);
        // release: wave-level vmcnt drain covers all wave-0 stores above
        if (tid == 0)
          __hip_atomic_fetch_add(&prog[grp * 256 + s], 1u,
                                 __ATOMIC_RELEASE, __HIP_MEMORY_SCOPE_AGENT);
      }
      // no third barrier (disjoint LDS words; mfma reads gated by next sync)
    }
  } else {
    // ================= decoder role =================
    // ---- phase 1: cooperative Wd -> WdT transpose ----
    {
      float* tile = (float*)smem;                          // 32x33 f32
      const int tx = tid & 31, ty = tid >> 5;              // ty 0..15
      const int r = tid >> 4, cc = tid & 15;
      for (int t = blockIdx.x - GRU_WGS; t < 16000; t += DEC_WGS) {
        int v0 = (t % 1000) * 32, h0 = (t / 1000) * 32;
        #pragma unroll
        for (int i = 0; i < 32; i += 16)
          tile[(ty + i) * 33 + tx] = Wd[(size_t)(h0 + ty + i) * NV + v0 + tx];
        __syncthreads();
        unsigned int pk = (unsigned int)f2bf(tile[(2 * cc) * 33 + r]) |
                          ((unsigned int)f2bf(tile[(2 * cc + 1) * 33 + r]) << 16);
        __hip_atomic_store(&WdTu[(size_t)(v0 + r) * 256 + (h0 >> 1) + cc], pk,
                           __ATOMIC_RELAXED, __HIP_MEMORY_SCOPE_AGENT);
        __syncthreads();
      }
      if (tid == 0) {
        __hip_atomic_fetch_add(done, 1u, __ATOMIC_RELEASE, __HIP_MEMORY_SCOPE_AGENT);
        while (__hip_atomic_load(done, __ATOMIC_RELAXED, __HIP_MEMORY_SCOPE_AGENT) < DEC_WGS)
          __builtin_amdgcn_s_sleep(8);
        (void)__hip_atomic_load(done, __ATOMIC_ACQUIRE, __HIP_MEMORY_SCOPE_AGENT);
      }
      __syncthreads();
    }
    // ---- phase 2: tile queue ----
    unsigned short* As = (unsigned short*)smem;            // 128x32 bf16, 8KB
    unsigned short* Bs = (unsigned short*)(smem + 8192);   // 128x32 bf16, 8KB
    unsigned int* tslot = (unsigned int*)(smem + 16384);
    const int wr = wave >> 2, wc = wave & 3;               // 2 x 4 wave grid
    int last_sc = -1;
    unsigned gmask = 0;

    for (;;) {
      if (tid == 0)
        *tslot = __hip_atomic_fetch_add(ctr, 1u, __ATOMIC_RELAXED, __HIP_MEMORY_SCOPE_AGENT);
      __syncthreads();
      unsigned t = *tslot;
      __syncthreads();
      if (t >= NTILES) break;
      const int sc = t / TILES_PER_SC;                     // 0..15 (16-step quanta)
      const int tt = t % TILES_PER_SC;
      const int ct = tt >> 1, bp = tt & 1;                 // bp: batches 0-7 / 8-15
      const int n0 = ct * 128;

      if (sc != last_sc) { last_sc = sc; gmask = 0; }
      const unsigned need = bp ? 0xCu : 0x3u;              // groups {2,3} or {0,1}
      if ((gmask & need) != need) {
        if (tid == 0) {
          #pragma unroll
          for (int g = 0; g < 4; ++g) if (need & (1u << g)) {
            const unsigned int* pp = &prog[g * 256 + sc * 16 + 15];
            while (__hip_atomic_load(pp, __ATOMIC_RELAXED, __HIP_MEMORY_SCOPE_AGENT) < 16u)
              __builtin_amdgcn_s_sleep(16);
          }
          (void)__hip_atomic_load(&prog[0], __ATOMIC_ACQUIRE, __HIP_MEMORY_SCOPE_AGENT);
        }
        __syncthreads();
        gmask |= need;
      }

      float4v acc[4][2] = {};
      for (int k0 = 0; k0 < NH; k0 += 32) {
        if (tid < 256) {
          #pragma unroll
          for (int qq = 0; qq < 2; ++qq) {
            int off = qq * 4096 + tid * 16;
            int rloc = off >> 6, cb = off & 63;
            int m = (bp * 8 + (rloc >> 4)) * 256 + sc * 16 + (rloc & 15);
            const char* ga = (const char*)Hall + (size_t)m * 1024 + k0 * 2 + cb;
            char* la = (char*)As + qq * 4096 + wave * 1024;
            __builtin_amdgcn_global_load_lds((gas_u32*)ga, (las_u32*)la, 16, 0, 0);
          }
        } else {
          int t2 = tid - 256;
          #pragma unroll
          for (int qq = 0; qq < 2; ++qq) {
            int off = qq * 4096 + t2 * 16;
            int rloc = off >> 6, cb = off & 63;
            const char* gb = (const char*)WdTu + (size_t)(n0 + rloc) * 1024 + k0 * 2 + cb;
            char* lb = (char*)Bs + qq * 4096 + (wave - 4) * 1024;
            __builtin_amdgcn_global_load_lds((gas_u32*)gb, (las_u32*)lb, 16, 0, 0);
          }
        }
        __syncthreads();
        short8v a[4], b2[2];
        #pragma unroll
        for (int i = 0; i < 4; ++i)
          a[i] = *(const short8v*)((const char*)As + (wr * 64 + i * 16 + lr) * 64 + lg * 16);
        #pragma unroll
        for (int j = 0; j < 2; ++j)
          b2[j] = *(const short8v*)((const char*)Bs + (wc * 32 + j * 16 + lr) * 64 + lg * 16);
        #pragma unroll
        for (int i = 0; i < 4; ++i) {
          #pragma unroll
          for (int j = 0; j < 2; ++j)
            acc[i][j] = __builtin_amdgcn_mfma_f32_16x16x32_bf16(a[i], b2[j], acc[i][j], 0, 0, 0);
        }
        __syncthreads();
      }
      #pragma unroll
      for (int i = 0; i < 4; ++i) {
        int rbase = wr * 64 + i * 16 + lg * 4;
        #pragma unroll
        for (int j = 0; j < 2; ++j) {
          int col = n0 + wc * 32 + j * 16 + lr;
          float bv = bd[col];
          #pragma unroll
          for (int rr = 0; rr < 4; ++rr) {
            int rloc = rbase + rr;
            int m = (bp * 8 + (rloc >> 4)) * 256 + sc * 16 + (rloc & 15);
            out[(size_t)m * NV + col] = acc[i][j][rr] + bv;
          }
        }
      }
    }
  }
}

// ---------------- launch ----------------
extern "C" void kernel_launch(void* const* d_in, const int* in_sizes, int n_in,
                              void* d_out, int out_size, void* d_ws, size_t ws_size,
                              hipStream_t stream) {
  const int*   x  = (const int*)d_in[0];
  const float* E  = (const float*)d_in[1];
  const float* W  = (const float*)d_in[2];
  const float* U  = (const float*)d_in[3];
  const float* bv = (const float*)d_in[4];
  const float* Wd = (const float*)d_in[5];
  const float* bd = (const float*)d_in[6];
  float* out = (float*)d_out;

  char* ws = (char*)d_ws;
  size_t off = 0;
  auto alloc = [&](size_t bytes) -> void* {
    void* p = ws + off;
    off = (off + bytes + 255) & ~(size_t)255;
    return p;
  };
  unsigned short* Aemb = (unsigned short*)alloc((size_t)NM * NE * 2);
  unsigned short* WT   = (unsigned short*)alloc((size_t)N3H * NE * 2);
  float*          UT   = (float*)alloc((size_t)N3H * NH * 4);
  unsigned short* xwb  = (unsigned short*)alloc((size_t)NM * N3H * 2);
  unsigned int*   WdTu = (unsigned int*)alloc((size_t)NV * NH * 2);
  unsigned int*   Hall = (unsigned int*)alloc((size_t)NM * NH * 2);
  unsigned int*   Hex  = (unsigned int*)alloc((size_t)257 * 4096 * 4);
  unsigned int*   prog = (unsigned int*)alloc((size_t)4 * 256 * 4);
  unsigned int*   ctr  = (unsigned int*)alloc(256);
  unsigned int*   done = (unsigned int*)alloc(256);

  hipMemsetAsync(Hex, 0xFF, (size_t)257 * 4096 * 4, stream);
  hipMemsetAsync(prog, 0, (size_t)4 * 256 * 4, stream);
  hipMemsetAsync(ctr, 0, 256, stream);
  hipMemsetAsync(done, 0, 256, stream);

  gather_emb<<<NM / 4, 256, 0, stream>>>(x, E, Aemb);
  transpose_conv<unsigned short><<<dim3(N3H / 32, NE / 32), dim3(32, 8), 0, stream>>>(W,  WT,  NE, N3H);
  transpose_conv<float>         <<<dim3(N3H / 32, NH / 32), dim3(32, 8), 0, stream>>>(U,  UT,  NH, N3H);

  gemm_bt<true><<<dim3(N3H / 128, NM / 128), 256, 0, stream>>>(Aemb, WT, bv, xwb, N3H, NE);

  fused_kernel<<<GRU_WGS + DEC_WGS, 512, 0, stream>>>(xwb, UT, bv, Wd, bd, WdTu,
                                                      Hall, Hex, prog, ctr, done, out);
}

// Round 7
// 955.338 us; speedup vs baseline: 1.6127x; 1.0771x over previous
//
#include <hip/hip_runtime.h>
#include <hip/hip_bf16.h>
#include <stdint.h>
#include <stddef.h>

// ---------------- problem dims ----------------
#define NB 16
#define NS 256
#define NH 512
#define NE 256
#define NV 32000
#define NM (NB*NS)        // 4096 flattened rows, m = b*256 + s
#define N3H 1536
#define GRU_WGS 64
#define DEC_WGS 192
#define TILES_PER_SC 500  // 250 ct * 2 bp
#define NTILES 8000       // 16 sc * 500

typedef __attribute__((ext_vector_type(8))) short short8v;
typedef __attribute__((ext_vector_type(4))) float float4v;
typedef __attribute__((address_space(1))) const unsigned int gas_u32;
typedef __attribute__((address_space(3))) unsigned int las_u32;

static __device__ __forceinline__ unsigned short f2bf(float f) {
  __hip_bfloat16 h = __float2bfloat16(f);
  return *reinterpret_cast<unsigned short*>(&h);
}
static __device__ __forceinline__ float bf2f(unsigned short u) {
  union { unsigned int u; float f; } c;
  c.u = ((unsigned int)u) << 16;
  return c.f;
}
static __device__ __forceinline__ float fast_tanh(float x) {
  float t = __expf(2.f * x);
  return (t - 1.f) / (t + 1.f);
}

// ---------------- embedding gather + convert to bf16 ----------------
__global__ void gather_emb(const int* __restrict__ x, const float* __restrict__ E,
                           unsigned short* __restrict__ A) {
  int m = blockIdx.x * 4 + (threadIdx.x >> 6);
  int lane = threadIdx.x & 63;
  int t = x[m];
  float4 v = reinterpret_cast<const float4*>(E + (size_t)t * NE)[lane];
  ushort4 o = make_ushort4(f2bf(v.x), f2bf(v.y), f2bf(v.z), f2bf(v.w));
  reinterpret_cast<ushort4*>(A + (size_t)m * NE)[lane] = o;
}

// ---------------- tiled transpose, f32 in -> (bf16|f32) out ----------------
template<typename T>
__global__ void transpose_conv(const float* __restrict__ in, T* __restrict__ out,
                               int R, int C) {
  __shared__ float tile[32][33];
  int c0 = blockIdx.x * 32, r0 = blockIdx.y * 32;
  int tx = threadIdx.x, ty = threadIdx.y;
  #pragma unroll
  for (int i = 0; i < 32; i += 8)
    tile[ty + i][tx] = in[(size_t)(r0 + ty + i) * C + (c0 + tx)];
  __syncthreads();
  #pragma unroll
  for (int i = 0; i < 32; i += 8) {
    float v = tile[tx][ty + i];
    if constexpr (sizeof(T) == 2)
      out[(size_t)(c0 + ty + i) * R + (r0 + tx)] = (T)f2bf(v);
    else
      out[(size_t)(c0 + ty + i) * R + (r0 + tx)] = (T)v;
  }
}

// ---------------- bf16 MFMA GEMM (xw = emb @ W + b0), XCD-swizzled --------
template<bool OUT_BF16>
__launch_bounds__(256)
__global__ void gemm_bt(const unsigned short* __restrict__ A,
                        const unsigned short* __restrict__ BT,
                        const float* __restrict__ bias,
                        void* __restrict__ out, int N, int K) {
  __shared__ unsigned short As[128 * 32];
  __shared__ unsigned short Bs[128 * 32];
  const int tid = threadIdx.x;
  const int lane = tid & 63, wave = tid >> 6;
  const int wr = wave >> 1, wc = wave & 1;
  int nwg = gridDim.x * gridDim.y;
  int bid0 = blockIdx.y * gridDim.x + blockIdx.x;
  int q = nwg >> 3, r8 = nwg & 7;
  int xcd = bid0 & 7, idx = bid0 >> 3;
  int bid = (xcd < r8 ? xcd * (q + 1) : r8 * (q + 1) + (xcd - r8) * q) + idx;
  const int m0 = (bid / gridDim.x) * 128, n0 = (bid % gridDim.x) * 128;
  const int lr = lane & 15, lg = lane >> 4;
  float4v acc[4][4] = {};

  for (int k0 = 0; k0 < K; k0 += 32) {
    #pragma unroll
    for (int qq = 0; qq < 2; ++qq) {
      int byteoff = qq * 4096 + tid * 16;
      int rr = byteoff >> 6, cb = byteoff & 63;
      const char* ga = (const char*)A + ((size_t)(m0 + rr) * K + k0) * 2 + cb;
      const char* gb = (const char*)BT + ((size_t)(n0 + rr) * K + k0) * 2 + cb;
      char* la = (char*)As + qq * 4096 + wave * 1024;
      char* lb = (char*)Bs + qq * 4096 + wave * 1024;
      __builtin_amdgcn_global_load_lds((gas_u32*)ga, (las_u32*)la, 16, 0, 0);
      __builtin_amdgcn_global_load_lds((gas_u32*)gb, (las_u32*)lb, 16, 0, 0);
    }
    __syncthreads();
    short8v a[4], b[4];
    #pragma unroll
    for (int i = 0; i < 4; ++i)
      a[i] = *(const short8v*)((const char*)As + (wr * 64 + i * 16 + lr) * 64 + lg * 16);
    #pragma unroll
    for (int j = 0; j < 4; ++j)
      b[j] = *(const short8v*)((const char*)Bs + (wc * 64 + j * 16 + lr) * 64 + lg * 16);
    #pragma unroll
    for (int i = 0; i < 4; ++i) {
      #pragma unroll
      for (int j = 0; j < 4; ++j)
        acc[i][j] = __builtin_amdgcn_mfma_f32_16x16x32_bf16(a[i], b[j], acc[i][j], 0, 0, 0);
    }
    __syncthreads();
  }
  #pragma unroll
  for (int i = 0; i < 4; ++i) {
    int row = m0 + wr * 64 + i * 16 + lg * 4;
    #pragma unroll
    for (int j = 0; j < 4; ++j) {
      int col = n0 + wc * 64 + j * 16 + lr;
      float bv = bias[col];
      #pragma unroll
      for (int rr = 0; rr < 4; ++rr) {
        float v = acc[i][j][rr] + bv;
        if constexpr (OUT_BF16)
          ((unsigned short*)out)[(size_t)(row + rr) * N + col] = f2bf(v);
        else
          ((float*)out)[(size_t)(row + rr) * N + col] = v;
      }
    }
  }
}

// ---------------- fused persistent GRU + overlapped decoder -----------------
// 256 WGs x 512 threads -> 1 WG/CU. Blocks 0..63: GRU. Blocks 64..255: decoder
// (phase 1 cooperative Wd->WdT transpose w/ NT loads; phase 2 tile queue with
// A read straight from Hex, NT logits stores to keep the LLC clean).
#define SENT 0xFFFFFFFFu
__launch_bounds__(512)
__global__ void fused_kernel(const unsigned short* __restrict__ xw,   // [4096][1536] bf16
                             const float* __restrict__ UT,            // [1536][512] f32
                             const float* __restrict__ bvec,          // b[2][1536] f32
                             const float* __restrict__ Wd,            // [512][32000] f32
                             const float* __restrict__ bd,            // [32000] f32
                             unsigned int* WdTu,                      // [32000][256] u32 (bf16 pairs)
                             unsigned int* Hex,                       // [257][4][1024] u32, memset 0xFF
                             unsigned int* prog,                      // [4][256] u32, memset 0
                             unsigned int* ctr,                       // tile counter, memset 0
                             unsigned int* done,                      // transpose barrier, memset 0
                             float* out) {                            // [4096][32000] f32
  const int tid = threadIdx.x;
  const int lane = tid & 63, wave = tid >> 6;
  const int lr = lane & 15, lg = lane >> 4;
  __shared__ __align__(16) char smem[16400];

  if (blockIdx.x < GRU_WGS) {
    // ================= GRU role =================
    __builtin_amdgcn_s_setprio(1);
    unsigned short* h_lds = (unsigned short*)smem;        // 4KB, swizzled
    float (*red)[100] = (float(*)[100])(smem + 4096);     // 1.6KB
    const int w = blockIdx.x;
    const int grp = w >> 4;          // batches 4*grp .. 4*grp+3
    const int wq = w & 15;           // h-dims 32*wq .. 32*wq+32

    // one-time: U slice -> VGPR B-fragments (waves 0..5)
    short8v Bf[16];
    if (wave < 6) {
      int c = wave * 16 + lr;                      // 0..95
      int g = c >> 5, dloc = c & 31;
      const float* up = UT + (size_t)(g * 512 + 32 * wq + dloc) * 512 + lg * 8;
      #pragma unroll
      for (int kk = 0; kk < 16; ++kk) {
        float4 v0 = *(const float4*)(up + kk * 32);
        float4 v1 = *(const float4*)(up + kk * 32 + 4);
        short8v t;
        t[0] = (short)f2bf(v0.x); t[1] = (short)f2bf(v0.y);
        t[2] = (short)f2bf(v0.z); t[3] = (short)f2bf(v0.w);
        t[4] = (short)f2bf(v1.x); t[5] = (short)f2bf(v1.y);
        t[6] = (short)f2bf(v1.z); t[7] = (short)f2bf(v1.w);
        Bf[kk] = t;
      }
    }
    for (int idx = tid; idx < 256; idx += 512)
      reinterpret_cast<uint4*>(h_lds)[idx] = make_uint4(0, 0, 0, 0);

    // gate-thread constants (tid < 64 = wave 0): (b_loc, dim-pair dp)
    float h0 = 0.f, h1 = 0.f;
    float bz0 = 0, bz1 = 0, br0 = 0, br1 = 0, bh0 = 0, bh1 = 0;
    const int b_loc = tid >> 4, dp = tid & 15;
    const unsigned int* xp = nullptr;
    if (tid < 64) {
      const float* brec = bvec + 1536;
      int d = 32 * wq + 2 * dp;
      int b = grp * 4 + b_loc;
      bz0 = brec[d];        bz1 = brec[d + 1];
      br0 = brec[512 + d];  br1 = brec[513 + d];
      bh0 = brec[1024 + d]; bh1 = brec[1025 + d];
      xp = (const unsigned int*)xw + ((size_t)(b * 256) * 1536 + d) / 2;
    }
    const int pb = tid >> 6;                       // b_loc of polled words (tid<256)
    const bool own = ((tid >> 2) & 15) == wq;
    __syncthreads();

    for (int s = 0; s < 256; ++s) {
      unsigned int xzw = 0, xrw = 0, xhw = 0;
      if (tid < 64) { xzw = xp[0]; xrw = xp[256]; xhw = xp[512]; xp += 768; }

      if (s > 0 && tid < 256 && !own) {
        const unsigned long long* src =
            (const unsigned long long*)(Hex + ((size_t)s * 4 + grp) * 1024 + tid * 4);
        unsigned long long v0 = __hip_atomic_load(&src[0], __ATOMIC_RELAXED, __HIP_MEMORY_SCOPE_AGENT);
        unsigned long long v1 = __hip_atomic_load(&src[1], __ATOMIC_RELAXED, __HIP_MEMORY_SCOPE_AGENT);
        unsigned int pend = 3;
        while (pend) {
          unsigned int np = 0;
          if (pend & 1) {
            if ((unsigned int)v0 != SENT && (unsigned int)(v0 >> 32) != SENT) {
              int dpp = (tid & 63) * 4;
              *(unsigned long long*)((char*)h_lds + ((pb * 1024 + dpp * 4) ^ (pb << 4))) = v0;
            } else np |= 1;
          }
          if (pend & 2) {
            if ((unsigned int)v1 != SENT && (unsigned int)(v1 >> 32) != SENT) {
              int dpp = (tid & 63) * 4 + 2;
              *(unsigned long long*)((char*)h_lds + ((pb * 1024 + dpp * 4) ^ (pb << 4))) = v1;
            } else np |= 2;
          }
          pend = np;
          if (pend) {
            __builtin_amdgcn_s_sleep(1);
            if (pend & 1) v0 = __hip_atomic_load(&src[0], __ATOMIC_RELAXED, __HIP_MEMORY_SCOPE_AGENT);
            if (pend & 2) v1 = __hip_atomic_load(&src[1], __ATOMIC_RELAXED, __HIP_MEMORY_SCOPE_AGENT);
          }
        }
      }
      __syncthreads();

      // rec = h(4x512) @ U_slice : waves 0..5, 16 cols each
      if (wave < 6) {
        float4v acc0 = {}, acc1 = {};
        #pragma unroll
        for (int kk = 0; kk < 16; ++kk) {
          int byteoff = ((lr & 3) * 1024 + kk * 64 + lg * 16) ^ ((lr & 3) << 4);
          short8v a = *(const short8v*)((const char*)h_lds + byteoff);
          if (kk & 1) acc1 = __builtin_amdgcn_mfma_f32_16x16x32_bf16(a, Bf[kk], acc1, 0, 0, 0);
          else        acc0 = __builtin_amdgcn_mfma_f32_16x16x32_bf16(a, Bf[kk], acc0, 0, 0, 0);
        }
        if (lg == 0) {
          int c = wave * 16 + lr;
          #pragma unroll
          for (int rr = 0; rr < 4; ++rr)
            red[rr][c] = acc0[rr] + acc1[rr];
        }
      }
      __syncthreads();

      // gates: 64 threads (wave 0), each owns (b_loc, dims 2dp, 2dp+1)
      if (tid < 64) {
        float rz0 = red[b_loc][2 * dp],      rz1 = red[b_loc][2 * dp + 1];
        float rr0 = red[b_loc][32 + 2 * dp], rr1 = red[b_loc][33 + 2 * dp];
        float rh0 = red[b_loc][64 + 2 * dp], rh1 = red[b_loc][65 + 2 * dp];
        float xz0 = bf2f((unsigned short)(xzw & 0xffff)), xz1 = bf2f((unsigned short)(xzw >> 16));
        float xr0 = bf2f((unsigned short)(xrw & 0xffff)), xr1 = bf2f((unsigned short)(xrw >> 16));
        float xh0 = bf2f((unsigned short)(xhw & 0xffff)), xh1 = bf2f((unsigned short)(xhw >> 16));
        float z0 = 1.f / (1.f + __expf(-(xz0 + rz0 + bz0)));
        float z1 = 1.f / (1.f + __expf(-(xz1 + rz1 + bz1)));
        float r0 = 1.f / (1.f + __expf(-(xr0 + rr0 + br0)));
        float r1 = 1.f / (1.f + __expf(-(xr1 + rr1 + br1)));
        float hh0 = fast_tanh(xh0 + r0 * (rh0 + bh0));
        float hh1 = fast_tanh(xh1 + r1 * (rh1 + bh1));
        h0 = z0 * h0 + (1.f - z0) * hh0;
        h1 = z1 * h1 + (1.f - z1) * hh1;
        unsigned int pack = (unsigned int)f2bf(h0) | ((unsigned int)f2bf(h1) << 16);
        int dpp = wq * 16 + dp;
        __hip_atomic_store(&Hex[((size_t)(s + 1) * 4 + grp) * 1024 + b_loc * 256 + dpp], pack,
                           __ATOMIC_RELAXED, __HIP_MEMORY_SCOPE_AGENT);
        *(unsigned int*)((char*)h_lds + ((b_loc * 1024 + dpp * 4) ^ (b_loc << 4))) = pack;
        // release: wave-level vmcnt drain covers all wave-0 stores above
        if (tid == 0)
          __hip_atomic_fetch_add(&prog[grp * 256 + s], 1u,
                                 __ATOMIC_RELEASE, __HIP_MEMORY_SCOPE_AGENT);
      }
      // no third barrier (disjoint LDS words; mfma reads gated by next sync)
    }
  } else {
    // ================= decoder role =================
    // ---- phase 1: cooperative Wd -> WdT transpose (NT loads) ----
    {
      float* tile = (float*)smem;                          // 32x33 f32
      const int tx = tid & 31, ty = tid >> 5;              // ty 0..15
      const int r = tid >> 4, cc = tid & 15;
      for (int t = blockIdx.x - GRU_WGS; t < 16000; t += DEC_WGS) {
        int v0 = (t % 1000) * 32, h0 = (t / 1000) * 32;
        #pragma unroll
        for (int i = 0; i < 32; i += 16)
          tile[(ty + i) * 33 + tx] =
              __builtin_nontemporal_load(&Wd[(size_t)(h0 + ty + i) * NV + v0 + tx]);
        __syncthreads();
        unsigned int pk = (unsigned int)f2bf(tile[(2 * cc) * 33 + r]) |
                          ((unsigned int)f2bf(tile[(2 * cc + 1) * 33 + r]) << 16);
        __hip_atomic_store(&WdTu[(size_t)(v0 + r) * 256 + (h0 >> 1) + cc], pk,
                           __ATOMIC_RELAXED, __HIP_MEMORY_SCOPE_AGENT);
        __syncthreads();
      }
      if (tid == 0) {
        __hip_atomic_fetch_add(done, 1u, __ATOMIC_RELEASE, __HIP_MEMORY_SCOPE_AGENT);
        while (__hip_atomic_load(done, __ATOMIC_RELAXED, __HIP_MEMORY_SCOPE_AGENT) < DEC_WGS)
          __builtin_amdgcn_s_sleep(8);
        (void)__hip_atomic_load(done, __ATOMIC_ACQUIRE, __HIP_MEMORY_SCOPE_AGENT);
      }
      __syncthreads();
    }
    // ---- phase 2: tile queue (A from Hex, NT logits stores) ----
    unsigned short* As = (unsigned short*)smem;            // 128x32 bf16, 8KB
    unsigned short* Bs = (unsigned short*)(smem + 8192);   // 128x32 bf16, 8KB
    unsigned int* tslot = (unsigned int*)(smem + 16384);
    const int wr = wave >> 2, wc = wave & 3;               // 2 x 4 wave grid
    int last_sc = -1;
    unsigned gmask = 0;

    for (;;) {
      if (tid == 0)
        *tslot = __hip_atomic_fetch_add(ctr, 1u, __ATOMIC_RELAXED, __HIP_MEMORY_SCOPE_AGENT);
      __syncthreads();
      unsigned t = *tslot;
      __syncthreads();
      if (t >= NTILES) break;
      const int sc = t / TILES_PER_SC;                     // 0..15 (16-step quanta)
      const int tt = t % TILES_PER_SC;
      const int ct = tt >> 1, bp = tt & 1;                 // bp: batches 0-7 / 8-15
      const int n0 = ct * 128;

      if (sc != last_sc) { last_sc = sc; gmask = 0; }
      const unsigned need = bp ? 0xCu : 0x3u;              // groups {2,3} or {0,1}
      if ((gmask & need) != need) {
        if (tid == 0) {
          #pragma unroll
          for (int g = 0; g < 4; ++g) if (need & (1u << g)) {
            const unsigned int* pp = &prog[g * 256 + sc * 16 + 15];
            while (__hip_atomic_load(pp, __ATOMIC_RELAXED, __HIP_MEMORY_SCOPE_AGENT) < 16u)
              __builtin_amdgcn_s_sleep(16);
          }
          (void)__hip_atomic_load(&prog[0], __ATOMIC_ACQUIRE, __HIP_MEMORY_SCOPE_AGENT);
        }
        __syncthreads();
        gmask |= need;
      }

      float4v acc[4][2] = {};
      for (int k0 = 0; k0 < NH; k0 += 32) {
        if (tid < 256) {
          #pragma unroll
          for (int qq = 0; qq < 2; ++qq) {
            int off = qq * 4096 + tid * 16;
            int rloc = off >> 6, cb = off & 63;
            int b = bp * 8 + (rloc >> 4);
            int s = sc * 16 + (rloc & 15);
            // h(s) for batch b lives at Hex[s+1][b>>2][b&3][0..255]
            const char* ga = (const char*)Hex +
                ((size_t)(((s + 1) * 4 + (b >> 2)) * 1024 + (b & 3) * 256)) * 4 + k0 * 2 + cb;
            char* la = (char*)As + qq * 4096 + wave * 1024;
            __builtin_amdgcn_global_load_lds((gas_u32*)ga, (las_u32*)la, 16, 0, 0);
          }
        } else {
          int t2 = tid - 256;
          #pragma unroll
          for (int qq = 0; qq < 2; ++qq) {
            int off = qq * 4096 + t2 * 16;
            int rloc = off >> 6, cb = off & 63;
            const char* gb = (const char*)WdTu + (size_t)(n0 + rloc) * 1024 + k0 * 2 + cb;
            char* lb = (char*)Bs + qq * 4096 + (wave - 4) * 1024;
            __builtin_amdgcn_global_load_lds((gas_u32*)gb, (las_u32*)lb, 16, 0, 0);
          }
        }
        __syncthreads();
        short8v a[4], b2[2];
        #pragma unroll
        for (int i = 0; i < 4; ++i)
          a[i] = *(const short8v*)((const char*)As + (wr * 64 + i * 16 + lr) * 64 + lg * 16);
        #pragma unroll
        for (int j = 0; j < 2; ++j)
          b2[j] = *(const short8v*)((const char*)Bs + (wc * 32 + j * 16 + lr) * 64 + lg * 16);
        #pragma unroll
        for (int i = 0; i < 4; ++i) {
          #pragma unroll
          for (int j = 0; j < 2; ++j)
            acc[i][j] = __builtin_amdgcn_mfma_f32_16x16x32_bf16(a[i], b2[j], acc[i][j], 0, 0, 0);
        }
        __syncthreads();
      }
      #pragma unroll
      for (int i = 0; i < 4; ++i) {
        int rbase = wr * 64 + i * 16 + lg * 4;
        #pragma unroll
        for (int j = 0; j < 2; ++j) {
          int col = n0 + wc * 32 + j * 16 + lr;
          float bv = bd[col];
          #pragma unroll
          for (int rr = 0; rr < 4; ++rr) {
            int rloc = rbase + rr;
            int m = (bp * 8 + (rloc >> 4)) * 256 + sc * 16 + (rloc & 15);
            __builtin_nontemporal_store(acc[i][j][rr] + bv, &out[(size_t)m * NV + col]);
          }
        }
      }
    }
  }
}

// ---------------- launch ----------------
extern "C" void kernel_launch(void* const* d_in, const int* in_sizes, int n_in,
                              void* d_out, int out_size, void* d_ws, size_t ws_size,
                              hipStream_t stream) {
  const int*   x  = (const int*)d_in[0];
  const float* E  = (const float*)d_in[1];
  const float* W  = (const float*)d_in[2];
  const float* U  = (const float*)d_in[3];
  const float* bv = (const float*)d_in[4];
  const float* Wd = (const float*)d_in[5];
  const float* bd = (const float*)d_in[6];
  float* out = (float*)d_out;

  char* ws = (char*)d_ws;
  size_t off = 0;
  auto alloc = [&](size_t bytes) -> void* {
    void* p = ws + off;
    off = (off + bytes + 255) & ~(size_t)255;
    return p;
  };
  unsigned short* Aemb = (unsigned short*)alloc((size_t)NM * NE * 2);
  unsigned short* WT   = (unsigned short*)alloc((size_t)N3H * NE * 2);
  float*          UT   = (float*)alloc((size_t)N3H * NH * 4);
  unsigned short* xwb  = (unsigned short*)alloc((size_t)NM * N3H * 2);
  unsigned int*   WdTu = (unsigned int*)alloc((size_t)NV * NH * 2);
  unsigned int*   Hex  = (unsigned int*)alloc((size_t)257 * 4096 * 4);
  unsigned int*   prog = (unsigned int*)alloc((size_t)4 * 256 * 4);
  unsigned int*   ctr  = (unsigned int*)alloc(256);
  unsigned int*   done = (unsigned int*)alloc(256);

  hipMemsetAsync(Hex, 0xFF, (size_t)257 * 4096 * 4, stream);
  hipMemsetAsync(prog, 0, (size_t)4 * 256 * 4, stream);
  hipMemsetAsync(ctr, 0, 256, stream);
  hipMemsetAsync(done, 0, 256, stream);

  gather_emb<<<NM / 4, 256, 0, stream>>>(x, E, Aemb);
  transpose_conv<unsigned short><<<dim3(N3H / 32, NE / 32), dim3(32, 8), 0, stream>>>(W,  WT,  NE, N3H);
  transpose_conv<float>         <<<dim3(N3H / 32, NH / 32), dim3(32, 8), 0, stream>>>(U,  UT,  NH, N3H);

  gemm_bt<true><<<dim3(N3H / 128, NM / 128), 256, 0, stream>>>(Aemb, WT, bv, xwb, N3H, NE);

  fused_kernel<<<GRU_WGS + DEC_WGS, 512, 0, stream>>>(xwb, UT, bv, Wd, bd, WdTu,
                                                      Hex, prog, ctr, done, out);
}

// Round 8
// 688.062 us; speedup vs baseline: 2.2392x; 1.3884x over previous
//
#include <hip/hip_runtime.h>
#include <hip/hip_bf16.h>
#include <stdint.h>
#include <stddef.h>

// ---------------- problem dims ----------------
#define NB 16
#define NS 256
#define NH 512
#define NE 256
#define NV 32000
#define NM (NB*NS)
#define N3H 1536

typedef __attribute__((ext_vector_type(8))) short short8v;
typedef __attribute__((ext_vector_type(4))) float float4v;
typedef __attribute__((address_space(1))) const unsigned int gas_u32;
typedef __attribute__((address_space(3))) unsigned int las_u32;

static __device__ __forceinline__ unsigned short f2bf(float f) {
  __hip_bfloat16 h = __float2bfloat16(f);
  return *reinterpret_cast<unsigned short*>(&h);
}
static __device__ __forceinline__ float bf2f(unsigned short u) {
  union { unsigned int u; float f; } c;
  c.u = ((unsigned int)u) << 16;
  return c.f;
}
static __device__ __forceinline__ float fast_tanh(float x) {
  float t = __expf(2.f * x);
  return (t - 1.f) / (t + 1.f);
}

// ---------------- embedding gather + convert to bf16 ----------------
__global__ void gather_emb(const int* __restrict__ x, const float* __restrict__ E,
                           unsigned short* __restrict__ A) {
  int m = blockIdx.x * 4 + (threadIdx.x >> 6);
  int lane = threadIdx.x & 63;
  int t = x[m];
  float4 v = reinterpret_cast<const float4*>(E + (size_t)t * NE)[lane];
  ushort4 o = make_ushort4(f2bf(v.x), f2bf(v.y), f2bf(v.z), f2bf(v.w));
  reinterpret_cast<ushort4*>(A + (size_t)m * NE)[lane] = o;
}

// ---------------- tiled transpose, f32 in -> (bf16|f32) out ----------------
template<typename T>
__global__ void transpose_conv(const float* __restrict__ in, T* __restrict__ out,
                               int R, int C) {
  __shared__ float tile[32][33];
  int c0 = blockIdx.x * 32, r0 = blockIdx.y * 32;
  int tx = threadIdx.x, ty = threadIdx.y;
  #pragma unroll
  for (int i = 0; i < 32; i += 8)
    tile[ty + i][tx] = in[(size_t)(r0 + ty + i) * C + (c0 + tx)];
  __syncthreads();
  #pragma unroll
  for (int i = 0; i < 32; i += 8) {
    float v = tile[tx][ty + i];
    if constexpr (sizeof(T) == 2)
      out[(size_t)(c0 + ty + i) * R + (r0 + tx)] = (T)f2bf(v);
    else
      out[(size_t)(c0 + ty + i) * R + (r0 + tx)] = (T)v;
  }
}

// ---------------- bf16 MFMA GEMM (xw = emb @ W + b0), XCD-swizzled --------
template<bool OUT_BF16>
__launch_bounds__(256)
__global__ void gemm_bt(const unsigned short* __restrict__ A,
                        const unsigned short* __restrict__ BT,
                        const float* __restrict__ bias,
                        void* __restrict__ out, int N, int K) {
  __shared__ unsigned short As[128 * 32];
  __shared__ unsigned short Bs[128 * 32];
  const int tid = threadIdx.x;
  const int lane = tid & 63, wave = tid >> 6;
  const int wr = wave >> 1, wc = wave & 1;
  int nwg = gridDim.x * gridDim.y;
  int bid0 = blockIdx.y * gridDim.x + blockIdx.x;
  int q = nwg >> 3, r8 = nwg & 7;
  int xcd = bid0 & 7, idx = bid0 >> 3;
  int bid = (xcd < r8 ? xcd * (q + 1) : r8 * (q + 1) + (xcd - r8) * q) + idx;
  const int m0 = (bid / gridDim.x) * 128, n0 = (bid % gridDim.x) * 128;
  const int lr = lane & 15, lg = lane >> 4;
  float4v acc[4][4] = {};

  for (int k0 = 0; k0 < K; k0 += 32) {
    #pragma unroll
    for (int qq = 0; qq < 2; ++qq) {
      int byteoff = qq * 4096 + tid * 16;
      int rr = byteoff >> 6, cb = byteoff & 63;
      const char* ga = (const char*)A + ((size_t)(m0 + rr) * K + k0) * 2 + cb;
      const char* gb = (const char*)BT + ((size_t)(n0 + rr) * K + k0) * 2 + cb;
      char* la = (char*)As + qq * 4096 + wave * 1024;
      char* lb = (char*)Bs + qq * 4096 + wave * 1024;
      __builtin_amdgcn_global_load_lds((gas_u32*)ga, (las_u32*)la, 16, 0, 0);
      __builtin_amdgcn_global_load_lds((gas_u32*)gb, (las_u32*)lb, 16, 0, 0);
    }
    __syncthreads();
    short8v a[4], b[4];
    #pragma unroll
    for (int i = 0; i < 4; ++i)
      a[i] = *(const short8v*)((const char*)As + (wr * 64 + i * 16 + lr) * 64 + lg * 16);
    #pragma unroll
    for (int j = 0; j < 4; ++j)
      b[j] = *(const short8v*)((const char*)Bs + (wc * 64 + j * 16 + lr) * 64 + lg * 16);
    #pragma unroll
    for (int i = 0; i < 4; ++i) {
      #pragma unroll
      for (int j = 0; j < 4; ++j)
        acc[i][j] = __builtin_amdgcn_mfma_f32_16x16x32_bf16(a[i], b[j], acc[i][j], 0, 0, 0);
    }
    __syncthreads();
  }
  #pragma unroll
  for (int i = 0; i < 4; ++i) {
    int row = m0 + wr * 64 + i * 16 + lg * 4;
    #pragma unroll
    for (int j = 0; j < 4; ++j) {
      int col = n0 + wc * 64 + j * 16 + lr;
      float bv = bias[col];
      #pragma unroll
      for (int rr = 0; rr < 4; ++rr) {
        float v = acc[i][j][rr] + bv;
        if constexpr (OUT_BF16)
          ((unsigned short*)out)[(size_t)(row + rr) * N + col] = f2bf(v);
        else
          ((float*)out)[(size_t)(row + rr) * N + col] = v;
      }
    }
  }
}

// ---------------- persistent GRU, 1-barrier step, in-wave gates -------------
// 64 WGs x 256 thr (4 waves). WG (grp = blk>>4 owns batches 4grp..4grp+3,
// wq = blk&15 owns dims 32wq..32wq+31). Wave w owns dims D0+8w..D0+8w+7:
// its 24 U-cols (z,r,h) live in VGPRs as 2 MFMA B-chains. Per step:
//   poll Hex[s] (data-as-flag, sentinel) -> h_lds[p]  -> ONE barrier ->
//   32 MFMA -> in-wave D-transpose via 384B LDS scratch (no barrier) ->
//   per-lane gates -> pack via shfl -> Hex[s+1] store + own-slice -> h_lds[p^1].
#define SENT 0xFFFFFFFFu
__launch_bounds__(256, 1)
__global__ void gru_kernel(const unsigned short* __restrict__ xw,   // [4096][1536] bf16
                           const float* __restrict__ UT,            // [1536][512] f32
                           const float* __restrict__ bvec,          // b[2][1536] f32
                           unsigned int* __restrict__ Hex) {        // [257][4][1024] u32, memset 0xFF
  const int blk = blockIdx.x, tid = threadIdx.x;
  const int grp = blk >> 4, wq = blk & 15;
  const int lane = tid & 63, w = tid >> 6;          // wave 0..3
  const int lr = lane & 15, lg = lane >> 4;
  __shared__ __align__(16) unsigned short h_lds[2][4 * 512];  // 8KB, swizzled
  __shared__ __align__(16) float scratch[4][96];              // per-wave D transpose

  const int D0 = 32 * wq;
  // ---- one-time: U cols -> VGPR B-fragments (2 chains per wave) ----
  short8v Bf0[16], Bf1[16];
  {
    int dloc = D0 + 8 * w + (lr & 7);
    int colg0 = (lr < 8) ? dloc : (512 + dloc);     // chain0: z(0-7), r(8-15)
    const float* u0 = UT + (size_t)colg0 * 512 + lg * 8;
    const float* u1 = UT + (size_t)(1024 + dloc) * 512 + lg * 8;  // chain1: h
    #pragma unroll
    for (int kk = 0; kk < 16; ++kk) {
      float4 a0 = *(const float4*)(u0 + kk * 32);
      float4 a1 = *(const float4*)(u0 + kk * 32 + 4);
      float4 c0 = *(const float4*)(u1 + kk * 32);
      float4 c1 = *(const float4*)(u1 + kk * 32 + 4);
      short8v t0, t1;
      t0[0] = (short)f2bf(a0.x); t0[1] = (short)f2bf(a0.y);
      t0[2] = (short)f2bf(a0.z); t0[3] = (short)f2bf(a0.w);
      t0[4] = (short)f2bf(a1.x); t0[5] = (short)f2bf(a1.y);
      t0[6] = (short)f2bf(a1.z); t0[7] = (short)f2bf(a1.w);
      t1[0] = (short)f2bf(c0.x); t1[1] = (short)f2bf(c0.y);
      t1[2] = (short)f2bf(c0.z); t1[3] = (short)f2bf(c0.w);
      t1[4] = (short)f2bf(c1.x); t1[5] = (short)f2bf(c1.y);
      t1[6] = (short)f2bf(c1.z); t1[7] = (short)f2bf(c1.w);
      Bf0[kk] = t0; Bf1[kk] = t1;
    }
  }
  for (int i = tid; i < 512; i += 256)
    reinterpret_cast<uint4*>(h_lds)[i] = make_uint4(0, 0, 0, 0);

  // ---- gate-lane constants (lane<32 of each wave): (b, di) -> dim d ----
  const int b = lane & 3, di = lane >> 2;           // valid for lane<32
  const int d = D0 + 8 * w + di;
  const int hi = di & 1;
  float h_old = 0.f, bz = 0.f, br = 0.f, bh = 0.f;
  const unsigned int* xp = nullptr;
  if (lane < 32) {
    const float* brec = bvec + 1536;
    bz = brec[d]; br = brec[512 + d]; bh = brec[1024 + d];
    xp = (const unsigned int*)xw + (size_t)(grp * 4 + b) * 256 * 768 + ((d & ~1) >> 1);
  }
  const bool own = ((tid >> 2) & 15) == wq;
  const int pbb = tid >> 6;                         // b of this thread's polled words
  __syncthreads();

  int p = 0;
  for (int s = 0; s < 256; ++s) {
    unsigned int xzw = 0, xrw = 0, xhw = 0;
    if (lane < 32) { xzw = xp[0]; xrw = xp[256]; xhw = xp[512]; xp += 768; }

    if (s > 0 && !own) {
      const unsigned long long* src =
          (const unsigned long long*)(Hex + ((size_t)s * 4 + grp) * 1024 + tid * 4);
      unsigned long long v0 = __hip_atomic_load(&src[0], __ATOMIC_RELAXED, __HIP_MEMORY_SCOPE_AGENT);
      unsigned long long v1 = __hip_atomic_load(&src[1], __ATOMIC_RELAXED, __HIP_MEMORY_SCOPE_AGENT);
      unsigned int pend = 3;
      char* dst = (char*)h_lds[p];
      int dpp = (tid & 63) * 4;
      while (pend) {
        unsigned int np = 0;
        if (pend & 1) {
          if ((unsigned int)v0 != SENT && (unsigned int)(v0 >> 32) != SENT)
            *(unsigned long long*)(dst + ((pbb * 1024 + dpp * 4) ^ (pbb << 4))) = v0;
          else np |= 1;
        }
        if (pend & 2) {
          if ((unsigned int)v1 != SENT && (unsigned int)(v1 >> 32) != SENT)
            *(unsigned long long*)(dst + ((pbb * 1024 + (dpp + 2) * 4) ^ (pbb << 4))) = v1;
          else np |= 2;
        }
        pend = np;
        if (pend) {
          __builtin_amdgcn_s_sleep(1);
          if (pend & 1) v0 = __hip_atomic_load(&src[0], __ATOMIC_RELAXED, __HIP_MEMORY_SCOPE_AGENT);
          if (pend & 2) v1 = __hip_atomic_load(&src[1], __ATOMIC_RELAXED, __HIP_MEMORY_SCOPE_AGENT);
        }
      }
    }
    __syncthreads();   // the only barrier per step

    // ---- rec: 2 MFMA chains on h_lds[p] ----
    float4v acc0 = {}, acc1 = {};
    const char* hb = (const char*)h_lds[p];
    #pragma unroll
    for (int kk = 0; kk < 16; ++kk) {
      int off = ((lane & 3) * 1024 + kk * 64 + lg * 16) ^ ((lane & 3) << 4);
      short8v a = *(const short8v*)(hb + off);
      acc0 = __builtin_amdgcn_mfma_f32_16x16x32_bf16(a, Bf0[kk], acc0, 0, 0, 0);
      acc1 = __builtin_amdgcn_mfma_f32_16x16x32_bf16(a, Bf1[kk], acc1, 0, 0, 0);
    }
    // ---- in-wave D transpose (rows=batches live at lg==0, regs 0-3) ----
    if (lg == 0) {
      *(float4*)&scratch[w][lr * 4] = *(float4*)&acc0;              // cols 0..15 (z,r)
      if (lr < 8)
        *(float4*)&scratch[w][64 + lr * 4] = *(float4*)&acc1;       // cols 16..23 (h)
    }
    // ---- gates: lanes 0..31, each owns (b, d) ----
    if (lane < 32) {
      float rz = scratch[w][lane];
      float rr = scratch[w][32 + lane];
      float rh = scratch[w][64 + lane];
      float xz = bf2f((unsigned short)(hi ? (xzw >> 16) : (xzw & 0xffff)));
      float xr = bf2f((unsigned short)(hi ? (xrw >> 16) : (xrw & 0xffff)));
      float xh = bf2f((unsigned short)(hi ? (xhw >> 16) : (xhw & 0xffff)));
      float z = 1.f / (1.f + __expf(-(xz + rz + bz)));
      float r = 1.f / (1.f + __expf(-(xr + rr + br)));
      float hh = fast_tanh(xh + r * (rh + bh));
      h_old = z * h_old + (1.f - z) * hh;
      unsigned int mine = f2bf(h_old);
      unsigned int part = (unsigned int)__shfl_xor((int)mine, 4);
      if ((lane & 4) == 0) {                        // even di: pack (d, d+1)
        unsigned int pack = mine | (part << 16);
        int wordi = b * 256 + wq * 16 + w * 4 + (di >> 1);
        __hip_atomic_store(&Hex[(size_t)(s + 1) * 4096 + grp * 1024 + wordi], pack,
                           __ATOMIC_RELAXED, __HIP_MEMORY_SCOPE_AGENT);
        *(unsigned int*)((char*)h_lds[p ^ 1] +
                         ((b * 1024 + (wordi & 255) * 4) ^ (b << 4))) = pack;
      }
    }
    p ^= 1;
  }
}

// ---------------- decoder GEMM: out = h @ Wd^T + bd (A read from Hex) -------
// 8000 blocks x 256 thr (~4-5 WGs/CU for TLP). bid n-major within XCD chunks
// so WdT panels stay XCD-L2-resident. NT f32 stores.
__launch_bounds__(256)
__global__ void dec_gemm(const char* __restrict__ HexB,             // Hex bytes
                         const unsigned short* __restrict__ WdT,    // [32000][512] bf16
                         const float* __restrict__ bd,
                         float* __restrict__ out) {
  __shared__ unsigned short As[128 * 32];
  __shared__ unsigned short Bs[128 * 32];
  const int tid = threadIdx.x;
  const int lane = tid & 63, wave = tid >> 6;
  const int wr = wave >> 1, wc = wave & 1;
  const int lr = lane & 15, lg = lane >> 4;
  int bid0 = blockIdx.x;
  int bid = (bid0 & 7) * 1000 + (bid0 >> 3);        // 8000 = 8 XCD chunks x 1000
  const int mt = bid & 31, nt = bid >> 5;           // 32 m-tiles, 250 n-tiles
  const int b = mt >> 1, s0 = (mt & 1) * 128;
  const int n0 = nt * 128;
  float4v acc[4][4] = {};

  for (int k0 = 0; k0 < NH; k0 += 32) {
    #pragma unroll
    for (int qq = 0; qq < 2; ++qq) {
      int off = qq * 4096 + tid * 16;
      int rloc = off >> 6, cb = off & 63;
      int s = s0 + rloc;
      const char* ga = HexB + ((size_t)(s + 1) * 4 + (b >> 2)) * 4096 +
                       (size_t)(b & 3) * 1024 + k0 * 2 + cb;
      const char* gb = (const char*)WdT + ((size_t)(n0 + rloc) * 512 + k0) * 2 + cb;
      __builtin_amdgcn_global_load_lds((gas_u32*)ga,
          (las_u32*)((char*)As + qq * 4096 + wave * 1024), 16, 0, 0);
      __builtin_amdgcn_global_load_lds((gas_u32*)gb,
          (las_u32*)((char*)Bs + qq * 4096 + wave * 1024), 16, 0, 0);
    }
    __syncthreads();
    short8v a[4], bb[4];
    #pragma unroll
    for (int i = 0; i < 4; ++i)
      a[i] = *(const short8v*)((const char*)As + (wr * 64 + i * 16 + lr) * 64 + lg * 16);
    #pragma unroll
    for (int j = 0; j < 4; ++j)
      bb[j] = *(const short8v*)((const char*)Bs + (wc * 64 + j * 16 + lr) * 64 + lg * 16);
    #pragma unroll
    for (int i = 0; i < 4; ++i) {
      #pragma unroll
      for (int j = 0; j < 4; ++j)
        acc[i][j] = __builtin_amdgcn_mfma_f32_16x16x32_bf16(a[i], bb[j], acc[i][j], 0, 0, 0);
    }
    __syncthreads();
  }
  #pragma unroll
  for (int i = 0; i < 4; ++i) {
    int l = wr * 64 + i * 16 + lg * 4;
    #pragma unroll
    for (int j = 0; j < 4; ++j) {
      int col = n0 + wc * 64 + j * 16 + lr;
      float bv = bd[col];
      #pragma unroll
      for (int rr = 0; rr < 4; ++rr) {
        size_t m = (size_t)(b * 256 + s0 + l + rr);
        __builtin_nontemporal_store(acc[i][j][rr] + bv, &out[m * NV + col]);
      }
    }
  }
}

// ---------------- launch ----------------
extern "C" void kernel_launch(void* const* d_in, const int* in_sizes, int n_in,
                              void* d_out, int out_size, void* d_ws, size_t ws_size,
                              hipStream_t stream) {
  const int*   x  = (const int*)d_in[0];
  const float* E  = (const float*)d_in[1];
  const float* W  = (const float*)d_in[2];
  const float* U  = (const float*)d_in[3];
  const float* bv = (const float*)d_in[4];
  const float* Wd = (const float*)d_in[5];
  const float* bd = (const float*)d_in[6];
  float* out = (float*)d_out;

  char* ws = (char*)d_ws;
  size_t off = 0;
  auto alloc = [&](size_t bytes) -> void* {
    void* p = ws + off;
    off = (off + bytes + 255) & ~(size_t)255;
    return p;
  };
  unsigned short* Aemb = (unsigned short*)alloc((size_t)NM * NE * 2);
  unsigned short* WT   = (unsigned short*)alloc((size_t)N3H * NE * 2);
  float*          UT   = (float*)alloc((size_t)N3H * NH * 4);
  unsigned short* xwb  = (unsigned short*)alloc((size_t)NM * N3H * 2);
  unsigned short* WdT  = (unsigned short*)alloc((size_t)NV * NH * 2);
  unsigned int*   Hex  = (unsigned int*)alloc((size_t)257 * 4096 * 4);

  hipMemsetAsync(Hex, 0xFF, (size_t)257 * 4096 * 4, stream);

  gather_emb<<<NM / 4, 256, 0, stream>>>(x, E, Aemb);
  transpose_conv<unsigned short><<<dim3(N3H / 32, NE / 32), dim3(32, 8), 0, stream>>>(W,  WT,  NE, N3H);
  transpose_conv<float>         <<<dim3(N3H / 32, NH / 32), dim3(32, 8), 0, stream>>>(U,  UT,  NH, N3H);
  transpose_conv<unsigned short><<<dim3(NV / 32,  NH / 32), dim3(32, 8), 0, stream>>>(Wd, WdT, NH, NV);

  gemm_bt<true><<<dim3(N3H / 128, NM / 128), 256, 0, stream>>>(Aemb, WT, bv, xwb, N3H, NE);

  gru_kernel<<<64, 256, 0, stream>>>(xwb, UT, bv, Hex);

  dec_gemm<<<8000, 256, 0, stream>>>((const char*)Hex, WdT, bd, out);
}

// Round 10
// 672.191 us; speedup vs baseline: 2.2921x; 1.0236x over previous
//
#include <hip/hip_runtime.h>
#include <hip/hip_bf16.h>
#include <stdint.h>
#include <stddef.h>

// ---------------- problem dims ----------------
#define NB 16
#define NS 256
#define NH 512
#define NE 256
#define NV 32000
#define NM (NB*NS)
#define N3H 1536

typedef __attribute__((ext_vector_type(8))) short short8v;
typedef __attribute__((ext_vector_type(4))) float float4v;
typedef __attribute__((address_space(1))) const unsigned int gas_u32;
typedef __attribute__((address_space(3))) unsigned int las_u32;

static __device__ __forceinline__ unsigned short f2bf(float f) {
  __hip_bfloat16 h = __float2bfloat16(f);
  return *reinterpret_cast<unsigned short*>(&h);
}
static __device__ __forceinline__ float bf2f(unsigned short u) {
  union { unsigned int u; float f; } c;
  c.u = ((unsigned int)u) << 16;
  return c.f;
}
static __device__ __forceinline__ float fast_tanh(float x) {
  float t = __expf(2.f * x);
  return (t - 1.f) / (t + 1.f);
}

// ---------------- embedding gather + convert to bf16 ----------------
__global__ void gather_emb(const int* __restrict__ x, const float* __restrict__ E,
                           unsigned short* __restrict__ A) {
  int m = blockIdx.x * 4 + (threadIdx.x >> 6);
  int lane = threadIdx.x & 63;
  int t = x[m];
  float4 v = reinterpret_cast<const float4*>(E + (size_t)t * NE)[lane];
  ushort4 o = make_ushort4(f2bf(v.x), f2bf(v.y), f2bf(v.z), f2bf(v.w));
  reinterpret_cast<ushort4*>(A + (size_t)m * NE)[lane] = o;
}

// ---------------- tiled transpose, f32 in -> (bf16|f32) out ----------------
template<typename T>
__global__ void transpose_conv(const float* __restrict__ in, T* __restrict__ out,
                               int R, int C) {
  __shared__ float tile[32][33];
  int c0 = blockIdx.x * 32, r0 = blockIdx.y * 32;
  int tx = threadIdx.x, ty = threadIdx.y;
  #pragma unroll
  for (int i = 0; i < 32; i += 8)
    tile[ty + i][tx] = in[(size_t)(r0 + ty + i) * C + (c0 + tx)];
  __syncthreads();
  #pragma unroll
  for (int i = 0; i < 32; i += 8) {
    float v = tile[tx][ty + i];
    if constexpr (sizeof(T) == 2)
      out[(size_t)(c0 + ty + i) * R + (r0 + tx)] = (T)f2bf(v);
    else
      out[(size_t)(c0 + ty + i) * R + (r0 + tx)] = (T)v;
  }
}

// ---------------- bf16 MFMA GEMM (xw = emb @ W + b0), XCD-swizzled --------
template<bool OUT_BF16>
__launch_bounds__(256)
__global__ void gemm_bt(const unsigned short* __restrict__ A,
                        const unsigned short* __restrict__ BT,
                        const float* __restrict__ bias,
                        void* __restrict__ out, int N, int K) {
  __shared__ unsigned short As[128 * 32];
  __shared__ unsigned short Bs[128 * 32];
  const int tid = threadIdx.x;
  const int lane = tid & 63, wave = tid >> 6;
  const int wr = wave >> 1, wc = wave & 1;
  int nwg = gridDim.x * gridDim.y;
  int bid0 = blockIdx.y * gridDim.x + blockIdx.x;
  int q = nwg >> 3, r8 = nwg & 7;
  int xcd = bid0 & 7, idx = bid0 >> 3;
  int bid = (xcd < r8 ? xcd * (q + 1) : r8 * (q + 1) + (xcd - r8) * q) + idx;
  const int m0 = (bid / gridDim.x) * 128, n0 = (bid % gridDim.x) * 128;
  const int lr = lane & 15, lg = lane >> 4;
  float4v acc[4][4] = {};

  for (int k0 = 0; k0 < K; k0 += 32) {
    #pragma unroll
    for (int qq = 0; qq < 2; ++qq) {
      int byteoff = qq * 4096 + tid * 16;
      int rr = byteoff >> 6, cb = byteoff & 63;
      const char* ga = (const char*)A + ((size_t)(m0 + rr) * K + k0) * 2 + cb;
      const char* gb = (const char*)BT + ((size_t)(n0 + rr) * K + k0) * 2 + cb;
      char* la = (char*)As + qq * 4096 + wave * 1024;
      char* lb = (char*)Bs + qq * 4096 + wave * 1024;
      __builtin_amdgcn_global_load_lds((gas_u32*)ga, (las_u32*)la, 16, 0, 0);
      __builtin_amdgcn_global_load_lds((gas_u32*)gb, (las_u32*)lb, 16, 0, 0);
    }
    __syncthreads();
    short8v a[4], b[4];
    #pragma unroll
    for (int i = 0; i < 4; ++i)
      a[i] = *(const short8v*)((const char*)As + (wr * 64 + i * 16 + lr) * 64 + lg * 16);
    #pragma unroll
    for (int j = 0; j < 4; ++j)
      b[j] = *(const short8v*)((const char*)Bs + (wc * 64 + j * 16 + lr) * 64 + lg * 16);
    #pragma unroll
    for (int i = 0; i < 4; ++i) {
      #pragma unroll
      for (int j = 0; j < 4; ++j)
        acc[i][j] = __builtin_amdgcn_mfma_f32_16x16x32_bf16(a[i], b[j], acc[i][j], 0, 0, 0);
    }
    __syncthreads();
  }
  #pragma unroll
  for (int i = 0; i < 4; ++i) {
    int row = m0 + wr * 64 + i * 16 + lg * 4;
    #pragma unroll
    for (int j = 0; j < 4; ++j) {
      int col = n0 + wc * 64 + j * 16 + lr;
      float bv = bias[col];
      #pragma unroll
      for (int rr = 0; rr < 4; ++rr) {
        float v = acc[i][j][rr] + bv;
        if constexpr (OUT_BF16)
          ((unsigned short*)out)[(size_t)(row + rr) * N + col] = f2bf(v);
        else
          ((float*)out)[(size_t)(row + rr) * N + col] = v;
      }
    }
  }
}

// ---------------- persistent GRU, LLC exchange, u64-aggregated publishes ----
// 64 WGs x 256 thr. grp = blk>>3 owns batches {2grp, 2grp+1}; wq = blk&7 owns
// dims [64wq, 64wq+64). Wave w owns 16 dims; its 48 U-cols (z,r,h) live in
// VGPRs as 3 MFMA B-chains. All exchange via agent-scope atomics (R8-proven).
// Per step: poll 1 u64/thread (own slice skipped) -> h_lds[p] -> ONE barrier
// -> 48 MFMA -> in-wave D-transpose via scratch -> per-lane gates -> shfl
// aggregation -> u64 atomic stores to Hex[s+1] + own-slice LDS write.
#define SENT 0xFFFFFFFFu
__launch_bounds__(256, 1)
__global__ void gru_kernel(const unsigned short* __restrict__ xw,   // [4096][1536] bf16
                           const float* __restrict__ UT,            // [1536][512] f32
                           const float* __restrict__ bvec,          // b[2][1536] f32
                           unsigned int* __restrict__ Hex) {        // [257][8][512] u32, memset 0xFF
  const int blk = blockIdx.x, tid = threadIdx.x;
  const int grp = blk >> 3, wq = blk & 7;
  const int lane = tid & 63, w = tid >> 6;
  const int lg = lane >> 4, lr = lane & 15;
  __shared__ __align__(16) unsigned short h_lds[2][1024];  // [parity][2 batches x 512]
  __shared__ __align__(16) float scratch[4][96];           // per-wave D transpose

  const int D0w = 64 * wq + 16 * w;   // this wave's 16 dims
  // ---- one-time: U cols -> VGPR B-fragments, 3 chains (z,r,h) ----
  short8v Bf[3][16];
  #pragma unroll
  for (int c = 0; c < 3; ++c) {
    const float* up = UT + (size_t)(c * 512 + D0w + lr) * 512 + lg * 8;
    #pragma unroll
    for (int kk = 0; kk < 16; ++kk) {
      float4 v0 = *(const float4*)(up + kk * 32);
      float4 v1 = *(const float4*)(up + kk * 32 + 4);
      short8v t;
      t[0] = (short)f2bf(v0.x); t[1] = (short)f2bf(v0.y);
      t[2] = (short)f2bf(v0.z); t[3] = (short)f2bf(v0.w);
      t[4] = (short)f2bf(v1.x); t[5] = (short)f2bf(v1.y);
      t[6] = (short)f2bf(v1.z); t[7] = (short)f2bf(v1.w);
      Bf[c][kk] = t;
    }
  }
  reinterpret_cast<uint4*>(h_lds)[tid] = make_uint4(0, 0, 0, 0);  // 256*16B = 4KB

  // ---- gate-lane constants (lane<32): b = lane&1, di = lane>>1 ----
  const int b = lane & 1, di = lane >> 1;
  const int d = D0w + di, hi = d & 1;
  float h_old = 0.f, bz = 0.f, br = 0.f, bh = 0.f;
  const unsigned int* xp = nullptr;
  if (lane < 32) {
    const float* brec = bvec + 1536;
    bz = brec[d]; br = brec[512 + d]; bh = brec[1024 + d];
    xp = (const unsigned int*)xw + (size_t)(grp * 2 + b) * 256 * 768 + (d >> 1);
  }
  // poll constants: thread t owns group-words 2t, 2t+1 (one u64)
  const bool own = ((tid >> 4) & 7) == wq;       // words within own 64-dim slice
  const int pbb = tid >> 7;                      // batch of polled words
  const int pm  = (2 * tid) & 255;               // within-batch word (even)
  __syncthreads();

  int p = 0;
  for (int s = 0; s < 256; ++s) {
    // xw prefetch for this step (in flight during poll)
    unsigned int xzw = 0, xrw = 0, xhw = 0;
    if (lane < 32) { xzw = xp[0]; xrw = xp[256]; xhw = xp[512]; xp += 768; }

    if (s > 0 && !own) {
      const unsigned long long* src =
          (const unsigned long long*)(Hex + (size_t)s * 4096 + grp * 512 + 2 * tid);
      unsigned long long v = __hip_atomic_load(src, __ATOMIC_RELAXED, __HIP_MEMORY_SCOPE_AGENT);
      while ((unsigned int)v == SENT || (unsigned int)(v >> 32) == SENT) {
        __builtin_amdgcn_s_sleep(1);
        v = __hip_atomic_load(src, __ATOMIC_RELAXED, __HIP_MEMORY_SCOPE_AGENT);
      }
      *(unsigned long long*)((char*)h_lds[p] + ((pbb * 1024 + pm * 4) ^ (pbb << 4))) = v;
    }
    __syncthreads();   // the only barrier per step

    // ---- rec: 3 independent MFMA chains on h_lds[p] ----
    float4v a0 = {}, a1 = {}, a2 = {};
    const char* hb = (const char*)h_lds[p];
    #pragma unroll
    for (int kk = 0; kk < 16; ++kk) {
      int off = ((lane & 1) * 1024 + kk * 64 + lg * 16) ^ ((lane & 1) << 4);
      short8v a = *(const short8v*)(hb + off);
      a0 = __builtin_amdgcn_mfma_f32_16x16x32_bf16(a, Bf[0][kk], a0, 0, 0, 0);
      a1 = __builtin_amdgcn_mfma_f32_16x16x32_bf16(a, Bf[1][kk], a1, 0, 0, 0);
      a2 = __builtin_amdgcn_mfma_f32_16x16x32_bf16(a, Bf[2][kk], a2, 0, 0, 0);
    }
    // in-wave D transpose: rows 0,1 (batches) live in lg==0 regs 0,1
    if (lg == 0) {
      *(float2*)&scratch[w][lr * 2]      = make_float2(a0[0], a0[1]);
      *(float2*)&scratch[w][32 + lr * 2] = make_float2(a1[0], a1[1]);
      *(float2*)&scratch[w][64 + lr * 2] = make_float2(a2[0], a2[1]);
    }
    // ---- gates: lanes 0..31, each owns (b, d) ----
    if (lane < 32) {
      float rz = scratch[w][di * 2 + b];
      float rr = scratch[w][32 + di * 2 + b];
      float rh = scratch[w][64 + di * 2 + b];
      float xz = bf2f((unsigned short)(hi ? (xzw >> 16) : (xzw & 0xffff)));
      float xr = bf2f((unsigned short)(hi ? (xrw >> 16) : (xrw & 0xffff)));
      float xh = bf2f((unsigned short)(hi ? (xhw >> 16) : (xhw & 0xffff)));
      float z = 1.f / (1.f + __expf(-(xz + rz + bz)));
      float r = 1.f / (1.f + __expf(-(xr + rr + br)));
      float hh = fast_tanh(xh + r * (rh + bh));
      h_old = z * h_old + (1.f - z) * hh;
      unsigned int mine = f2bf(h_old);
      // dword pack (dims d, d+1) on lanes with even di
      unsigned int pack = mine | ((unsigned int)__shfl_xor((int)mine, 2) << 16);
      // u64 pack (words m, m+1) from partner lane+4
      unsigned int hip2 = (unsigned int)__shfl_xor((int)pack, 4);
      if ((lane & 6) == 0) {                     // lanes 0,1,8,9,16,17,24,25
        unsigned long long u = (unsigned long long)pack | ((unsigned long long)hip2 << 32);
        int m = 32 * wq + 8 * w + 2 * (lane >> 3);          // within-batch word
        __hip_atomic_store((unsigned long long*)&Hex[(size_t)(s + 1) * 4096 + grp * 512 +
                                                     b * 256 + m],
                           u, __ATOMIC_RELAXED, __HIP_MEMORY_SCOPE_AGENT);
        *(unsigned long long*)((char*)h_lds[p ^ 1] + ((b * 1024 + m * 4) ^ (b << 4))) = u;
      }
    }
    p ^= 1;
  }
}

// ---------------- decoder GEMM: out = h @ Wd^T + bd (A read from Hex) -------
// 8000 blocks x 256 thr (~4 WGs/CU). bid n-major within 8 XCD chunks so WdT
// panels stay XCD-L2-resident. NT f32 stores.
__launch_bounds__(256)
__global__ void dec_gemm(const char* __restrict__ HexB,             // Hex bytes
                         const unsigned short* __restrict__ WdT,    // [32000][512] bf16
                         const float* __restrict__ bd,
                         float* __restrict__ out) {
  __shared__ unsigned short As[128 * 32];
  __shared__ unsigned short Bs[128 * 32];
  const int tid = threadIdx.x;
  const int lane = tid & 63, wave = tid >> 6;
  const int wr = wave >> 1, wc = wave & 1;
  const int lr = lane & 15, lg = lane >> 4;
  int bid0 = blockIdx.x;
  int bid = (bid0 & 7) * 1000 + (bid0 >> 3);        // 8000 = 8 XCD chunks x 1000
  const int mt = bid & 31, nt = bid >> 5;           // 32 m-tiles, 250 n-tiles
  const int b = mt >> 1, s0 = (mt & 1) * 128;
  const int n0 = nt * 128;
  float4v acc[4][4] = {};

  for (int k0 = 0; k0 < NH; k0 += 32) {
    #pragma unroll
    for (int qq = 0; qq < 2; ++qq) {
      int off = qq * 4096 + tid * 16;
      int rloc = off >> 6, cb = off & 63;
      int s = s0 + rloc;
      // h(s) for batch b lives at Hex[s+1][b>>1][b&1][0..255] (1KB row)
      const char* ga = HexB + ((size_t)(s + 1) * 4096 + (b >> 1) * 512 + (b & 1) * 256) * 4
                       + k0 * 2 + cb;
      const char* gb = (const char*)WdT + ((size_t)(n0 + rloc) * 512 + k0) * 2 + cb;
      __builtin_amdgcn_global_load_lds((gas_u32*)ga,
          (las_u32*)((char*)As + qq * 4096 + wave * 1024), 16, 0, 0);
      __builtin_amdgcn_global_load_lds((gas_u32*)gb,
          (las_u32*)((char*)Bs + qq * 4096 + wave * 1024), 16, 0, 0);
    }
    __syncthreads();
    short8v a[4], bb[4];
    #pragma unroll
    for (int i = 0; i < 4; ++i)
      a[i] = *(const short8v*)((const char*)As + (wr * 64 + i * 16 + lr) * 64 + lg * 16);
    #pragma unroll
    for (int j = 0; j < 4; ++j)
      bb[j] = *(const short8v*)((const char*)Bs + (wc * 64 + j * 16 + lr) * 64 + lg * 16);
    #pragma unroll
    for (int i = 0; i < 4; ++i) {
      #pragma unroll
      for (int j = 0; j < 4; ++j)
        acc[i][j] = __builtin_amdgcn_mfma_f32_16x16x32_bf16(a[i], bb[j], acc[i][j], 0, 0, 0);
    }
    __syncthreads();
  }
  #pragma unroll
  for (int i = 0; i < 4; ++i) {
    int l = wr * 64 + i * 16 + lg * 4;
    #pragma unroll
    for (int j = 0; j < 4; ++j) {
      int col = n0 + wc * 64 + j * 16 + lr;
      float bv = bd[col];
      #pragma unroll
      for (int rr = 0; rr < 4; ++rr) {
        size_t m = (size_t)(b * 256 + s0 + l + rr);
        __builtin_nontemporal_store(acc[i][j][rr] + bv, &out[m * NV + col]);
      }
    }
  }
}

// ---------------- launch ----------------
extern "C" void kernel_launch(void* const* d_in, const int* in_sizes, int n_in,
                              void* d_out, int out_size, void* d_ws, size_t ws_size,
                              hipStream_t stream) {
  const int*   x  = (const int*)d_in[0];
  const float* E  = (const float*)d_in[1];
  const float* W  = (const float*)d_in[2];
  const float* U  = (const float*)d_in[3];
  const float* bv = (const float*)d_in[4];
  const float* Wd = (const float*)d_in[5];
  const float* bd = (const float*)d_in[6];
  float* out = (float*)d_out;

  char* ws = (char*)d_ws;
  size_t off = 0;
  auto alloc = [&](size_t bytes) -> void* {
    void* p = ws + off;
    off = (off + bytes + 255) & ~(size_t)255;
    return p;
  };
  unsigned short* Aemb = (unsigned short*)alloc((size_t)NM * NE * 2);
  unsigned short* WT   = (unsigned short*)alloc((size_t)N3H * NE * 2);
  float*          UT   = (float*)alloc((size_t)N3H * NH * 4);
  unsigned short* xwb  = (unsigned short*)alloc((size_t)NM * N3H * 2);
  unsigned short* WdT  = (unsigned short*)alloc((size_t)NV * NH * 2);
  unsigned int*   Hex  = (unsigned int*)alloc((size_t)257 * 4096 * 4);

  hipMemsetAsync(Hex, 0xFF, (size_t)257 * 4096 * 4, stream);

  gather_emb<<<NM / 4, 256, 0, stream>>>(x, E, Aemb);
  transpose_conv<unsigned short><<<dim3(N3H / 32, NE / 32), dim3(32, 8), 0, stream>>>(W,  WT,  NE, N3H);
  transpose_conv<float>         <<<dim3(N3H / 32, NH / 32), dim3(32, 8), 0, stream>>>(U,  UT,  NH, N3H);
  transpose_conv<unsigned short><<<dim3(NV / 32,  NH / 32), dim3(32, 8), 0, stream>>>(Wd, WdT, NH, NV);

  gemm_bt<true><<<dim3(N3H / 128, NM / 128), 256, 0, stream>>>(Aemb, WT, bv, xwb, N3H, NE);

  gru_kernel<<<64, 256, 0, stream>>>(xwb, UT, bv, Hex);

  dec_gemm<<<8000, 256, 0, stream>>>((const char*)Hex, WdT, bd, out);
}